// Round 1
// baseline (1432.436 us; speedup 1.0000x reference)
//
#include <hip/hip_runtime.h>
#include <hip/hip_bf16.h>
#include <math.h>

// Problem constants
#define Bb 8
#define Tt 1024
#define Jj 25
#define D_MODEL 256
#define D_STATE 16
#define D_CONV 4
#define D_INNER 512
#define DT_RANK 16
#define N_CLASSES 60
#define Mrows (Bb*Tt)   // 8192

// ---------------------------------------------------------------------------
// Kernel 1: featurize -> featraw (M, 225)
// feat[b,t, j*9+cc]: cc/3 = kind (0 pos, 1 vel, 2 acc), cc%3 = comp
// pos[t] = x[b,t,j,:] - x[b,t,0,:]; vel[t]=pos[t]-pos[t-1] (t>=1); acc=vel diff
// ---------------------------------------------------------------------------
__global__ __launch_bounds__(256) void feat_kernel(const float* __restrict__ x,
                                                   float* __restrict__ featraw) {
    int r = blockIdx.x;          // 0..8191 (b*T+t)
    int c = threadIdx.x;         // 0..255, valid < 225
    if (c >= 225) return;
    int t = r & (Tt - 1);
    int j = c / 9;
    int cc = c - j * 9;
    int comp = cc % 3;
    int kind = cc / 3;

    auto POS = [&](int dt) -> float {
        const float* p = x + (long)(r - dt) * Jj * 3;
        return p[j * 3 + comp] - p[comp];
    };

    float v;
    if (kind == 0) {
        v = POS(0);
    } else if (kind == 1) {
        v = (t >= 1) ? (POS(0) - POS(1)) : 0.f;
    } else {
        if (t >= 2)      v = POS(0) - 2.f * POS(1) + POS(2);
        else if (t == 1) v = POS(0) - POS(1);
        else             v = 0.f;
    }
    featraw[(long)r * 225 + c] = v;
}

// ---------------------------------------------------------------------------
// Generic tiled fp32 GEMM: C[M,N] = epi( A[M,K](lda) @ W[N,K]^T + bias )
// epi: 0=none, 1=+bias, 2=+bias then softplus, 3=+resid
// ---------------------------------------------------------------------------
#define BM 64
#define BN 64
#define BK 16

__global__ __launch_bounds__(256) void gemm_kernel(
    const float* __restrict__ A, int lda,
    const float* __restrict__ W,
    const float* __restrict__ bias,
    const float* __restrict__ resid, int ldr,
    float* __restrict__ C, int ldc,
    int M, int N, int K, int epi)
{
    __shared__ float As[BK][BM + 1];
    __shared__ float Ws[BK][BN + 1];
    int tid = threadIdx.x;
    int m0 = blockIdx.y * BM;
    int n0 = blockIdx.x * BN;
    int tx = tid & 15, ty = tid >> 4;
    int lr = tid >> 2;          // 0..63
    int lk = (tid & 3) * 4;     // 0,4,8,12
    float acc[4][4] = {};

    for (int k0 = 0; k0 < K; k0 += BK) {
        int gm = m0 + lr;
        int gn = n0 + lr;
#pragma unroll
        for (int i = 0; i < 4; i++) {
            int gk = k0 + lk + i;
            As[lk + i][lr] = (gm < M && gk < K) ? A[(long)gm * lda + gk] : 0.f;
            Ws[lk + i][lr] = (gn < N && gk < K) ? W[(long)gn * K + gk] : 0.f;
        }
        __syncthreads();
#pragma unroll
        for (int kk = 0; kk < BK; kk++) {
            float a[4], w[4];
#pragma unroll
            for (int i = 0; i < 4; i++) a[i] = As[kk][ty * 4 + i];
#pragma unroll
            for (int j = 0; j < 4; j++) w[j] = Ws[kk][tx * 4 + j];
#pragma unroll
            for (int i = 0; i < 4; i++)
#pragma unroll
                for (int j = 0; j < 4; j++)
                    acc[i][j] += a[i] * w[j];
        }
        __syncthreads();
    }

#pragma unroll
    for (int i = 0; i < 4; i++) {
        int gm = m0 + ty * 4 + i;
        if (gm >= M) continue;
#pragma unroll
        for (int j = 0; j < 4; j++) {
            int gn = n0 + tx * 4 + j;
            if (gn >= N) continue;
            float v = acc[i][j];
            if (epi == 1 || epi == 2) v += bias[gn];
            if (epi == 2) v = fmaxf(v, 0.f) + log1pf(expf(-fabsf(v)));
            if (epi == 3) v += resid[(long)gm * ldr + gn];
            C[(long)gm * ldc + gn] = v;
        }
    }
}

// ---------------------------------------------------------------------------
// LayerNorm over D=256 per row (8192 rows). out = (x-mu)*rsqrt(var+eps)*g + b
// ---------------------------------------------------------------------------
__global__ __launch_bounds__(256) void ln_kernel(const float* __restrict__ x,
                                                 const float* __restrict__ g,
                                                 const float* __restrict__ b,
                                                 float* __restrict__ out) {
    __shared__ float red[256];
    long r = blockIdx.x;
    int d = threadIdx.x;
    float v = x[r * 256 + d];
    red[d] = v;
    __syncthreads();
    for (int s = 128; s > 0; s >>= 1) {
        if (d < s) red[d] += red[d + s];
        __syncthreads();
    }
    float mu = red[0] * (1.f / 256.f);
    __syncthreads();
    float dv = v - mu;
    red[d] = dv * dv;
    __syncthreads();
    for (int s = 128; s > 0; s >>= 1) {
        if (d < s) red[d] += red[d + s];
        __syncthreads();
    }
    float var = red[0] * (1.f / 256.f);
    out[r * 256 + d] = dv * rsqrtf(var + 1e-5f) * g[d] + b[d];
}

// ---------------------------------------------------------------------------
// Causal depthwise conv (k=4) + SiLU.  xz (M,1024), xm half = cols 0..511.
// xm_out[r,d] = silu( sum_k w[d,k]*xz[r-3+k, d] + cb[d] )
// ---------------------------------------------------------------------------
__global__ __launch_bounds__(256) void conv_silu_kernel(const float* __restrict__ xz,
                                                        const float* __restrict__ cw,
                                                        const float* __restrict__ cb,
                                                        float* __restrict__ xm) {
    int r = blockIdx.x;                      // 0..8191
    int d = blockIdx.y * 256 + threadIdx.x;  // 0..511
    int t = r & (Tt - 1);
    float w0 = cw[d * 4 + 0], w1 = cw[d * 4 + 1], w2 = cw[d * 4 + 2], w3 = cw[d * 4 + 3];
    float acc = cb[d];
    acc += w3 * xz[(long)r * 1024 + d];
    if (t >= 1) acc += w2 * xz[(long)(r - 1) * 1024 + d];
    if (t >= 2) acc += w1 * xz[(long)(r - 2) * 1024 + d];
    if (t >= 3) acc += w0 * xz[(long)(r - 3) * 1024 + d];
    float s = acc / (1.f + expf(-acc));
    xm[(long)r * 512 + d] = s;
}

// ---------------------------------------------------------------------------
// Selective scan. One lane per (b,d). h[16] in registers. Fuses +u*D and
// *silu(res). Writes y in-place over the delta buffer.
// delta (M,512), u=xm (M,512), dbl (M,48) [B at +16, C at +32], xz res at +512
// ---------------------------------------------------------------------------
__global__ __launch_bounds__(64) void scan_kernel(const float* __restrict__ delta,
                                                  const float* __restrict__ u_,
                                                  const float* __restrict__ dbl,
                                                  const float* __restrict__ xz,
                                                  const float* __restrict__ A_log,
                                                  const float* __restrict__ Dv,
                                                  float* __restrict__ y) {
    int b = blockIdx.x;                 // 0..7
    int d = blockIdx.y * 64 + threadIdx.x;  // 0..511
    float Arow[16];
#pragma unroll
    for (int n = 0; n < 16; n++) Arow[n] = -expf(A_log[d * 16 + n]);
    float Dd = Dv[d];
    float h[16];
#pragma unroll
    for (int n = 0; n < 16; n++) h[n] = 0.f;

    for (int t = 0; t < Tt; t++) {
        long r = (long)b * Tt + t;
        float dl = delta[r * 512 + d];
        float u = u_[r * 512 + d];
        float res = xz[r * 1024 + 512 + d];
        float du = dl * u;

        float Bn[16], Cn[16];
        const float4* Bp = (const float4*)(dbl + r * 48 + 16);
        const float4* Cp = (const float4*)(dbl + r * 48 + 32);
#pragma unroll
        for (int q = 0; q < 4; q++) {
            float4 bv = Bp[q];
            float4 cv = Cp[q];
            Bn[q * 4 + 0] = bv.x; Bn[q * 4 + 1] = bv.y; Bn[q * 4 + 2] = bv.z; Bn[q * 4 + 3] = bv.w;
            Cn[q * 4 + 0] = cv.x; Cn[q * 4 + 1] = cv.y; Cn[q * 4 + 2] = cv.z; Cn[q * 4 + 3] = cv.w;
        }

        float ysum = 0.f;
#pragma unroll
        for (int n = 0; n < 16; n++) {
            float dA = expf(dl * Arow[n]);
            h[n] = dA * h[n] + du * Bn[n];
            ysum += h[n] * Cn[n];
        }
        float yy = ysum + u * Dd;
        float sres = res / (1.f + expf(-res));
        y[r * 512 + d] = yy * sres;
    }
}

// ---------------------------------------------------------------------------
// Pool: partial sums of post-LN rows -> pooled[b,256] (atomic, 16 per addr)
// ---------------------------------------------------------------------------
__global__ __launch_bounds__(256) void pool_kernel(const float* __restrict__ fn,
                                                   float* __restrict__ pooled) {
    int b = blockIdx.x;
    int q = blockIdx.y;   // 16 chunks of 64 rows
    int d = threadIdx.x;
    float s = 0.f;
    for (int i = 0; i < 64; i++) {
        long t = q * 64 + i;
        s += fn[((long)b * Tt + t) * 256 + d];
    }
    atomicAdd(&pooled[b * 256 + d], s);
}

// ---------------------------------------------------------------------------
// Head: out[b,n] = (pooled[b,:]/T) . fine_w[n,:] + fine_b[n]
// ---------------------------------------------------------------------------
__global__ __launch_bounds__(64) void head_kernel(const float* __restrict__ pooled,
                                                  const float* __restrict__ fw,
                                                  const float* __restrict__ fb,
                                                  float* __restrict__ out) {
    int b = blockIdx.x;
    int n = threadIdx.x;
    if (n >= N_CLASSES) return;
    float s = 0.f;
    for (int k = 0; k < 256; k++) s += pooled[b * 256 + k] * fw[n * 256 + k];
    out[b * N_CLASSES + n] = s * (1.f / (float)Tt) + fb[n];
}

// ---------------------------------------------------------------------------
extern "C" void kernel_launch(void* const* d_in, const int* in_sizes, int n_in,
                              void* d_out, int out_size, void* d_ws, size_t ws_size,
                              hipStream_t stream) {
    const float* x         = (const float*)d_in[0];
    const float* embed_w   = (const float*)d_in[1];
    const float* embed_b   = (const float*)d_in[2];
    const float* pre_g     = (const float*)d_in[3];
    const float* pre_b     = (const float*)d_in[4];
    const float* in_proj_w = (const float*)d_in[5];
    const float* conv_w    = (const float*)d_in[6];
    const float* conv_b    = (const float*)d_in[7];
    const float* x_proj_w  = (const float*)d_in[8];
    const float* dt_proj_w = (const float*)d_in[9];
    const float* dt_proj_b = (const float*)d_in[10];
    const float* A_log     = (const float*)d_in[11];
    const float* Dv        = (const float*)d_in[12];
    const float* out_proj_w= (const float*)d_in[13];
    const float* post_g    = (const float*)d_in[14];
    const float* post_b    = (const float*)d_in[15];
    const float* fine_w    = (const float*)d_in[16];
    const float* fine_b    = (const float*)d_in[17];
    float* out = (float*)d_out;
    float* ws  = (float*)d_ws;

    // workspace layout (floats)
    float* featraw = ws;                        // 1,843,200  (reused as dbl)
    float* feat    = ws + 1843200;              // 2,097,152
    float* hn      = feat + 2097152;            // 2,097,152  (reused as post-LN out)
    float* xz      = hn + 2097152;              // 8,388,608
    float* xm      = xz + 8388608;              // 4,194,304
    float* delta   = xm + 4194304;              // 4,194,304  (scan writes y in-place)
    float* pooled  = delta + 4194304;           // 2,048
    float* dbl     = featraw;                   // (M,48) fits in dead featraw

    // 1. featurize
    feat_kernel<<<dim3(Mrows), dim3(256), 0, stream>>>(x, featraw);

    // 2. embed: feat = featraw @ embed_w^T + embed_b   (K=225, N=256)
    gemm_kernel<<<dim3(4, 128), dim3(256), 0, stream>>>(
        featraw, 225, embed_w, embed_b, nullptr, 0, feat, 256, Mrows, 256, 225, 1);

    // 3. pre layernorm -> hn
    ln_kernel<<<dim3(Mrows), dim3(256), 0, stream>>>(feat, pre_g, pre_b, hn);

    // 4. in_proj: xz = hn @ in_proj_w^T  (K=256, N=1024)
    gemm_kernel<<<dim3(16, 128), dim3(256), 0, stream>>>(
        hn, 256, in_proj_w, nullptr, nullptr, 0, xz, 1024, Mrows, 1024, 256, 0);

    // 5. conv + silu -> xm
    conv_silu_kernel<<<dim3(Mrows, 2), dim3(256), 0, stream>>>(xz, conv_w, conv_b, xm);

    // 6. x_proj: dbl = xm @ x_proj_w^T  (K=512, N=48)
    gemm_kernel<<<dim3(1, 128), dim3(256), 0, stream>>>(
        xm, 512, x_proj_w, nullptr, nullptr, 0, dbl, 48, Mrows, 48, 512, 0);

    // 7. dt_proj + softplus: delta = softplus(dbl[:, :16] @ dt_proj_w^T + b)  (K=16, N=512)
    gemm_kernel<<<dim3(8, 128), dim3(256), 0, stream>>>(
        dbl, 48, dt_proj_w, dt_proj_b, nullptr, 0, delta, 512, Mrows, 512, 16, 2);

    // 8. selective scan (y written in-place over delta)
    scan_kernel<<<dim3(8, 8), dim3(64), 0, stream>>>(delta, xm, dbl, xz, A_log, Dv, delta);

    // 9. out_proj + residual: feat = feat + y @ out_proj_w^T  (K=512, N=256)
    gemm_kernel<<<dim3(4, 128), dim3(256), 0, stream>>>(
        delta, 512, out_proj_w, nullptr, feat, 256, feat, 256, Mrows, 256, 512, 3);

    // 10. post layernorm -> hn (reuse)
    ln_kernel<<<dim3(Mrows), dim3(256), 0, stream>>>(feat, post_g, post_b, hn);

    // 11. pool
    hipMemsetAsync(pooled, 0, Bb * 256 * sizeof(float), stream);
    pool_kernel<<<dim3(Bb, 16), dim3(256), 0, stream>>>(hn, pooled);

    // 12. head
    head_kernel<<<dim3(Bb), dim3(64), 0, stream>>>(pooled, fine_w, fine_b, out);
}

// Round 2
// 651.619 us; speedup vs baseline: 2.1983x; 2.1983x over previous
//
#include <hip/hip_runtime.h>
#include <hip/hip_bf16.h>
#include <math.h>

// Problem constants
#define Bb 8
#define Tt 1024
#define Jj 25
#define D_MODEL 256
#define D_STATE 16
#define D_CONV 4
#define D_INNER 512
#define DT_RANK 16
#define N_CLASSES 60
#define Mrows (Bb*Tt)   // 8192
#define NC 32           // scan chunks
#define CL 32           // chunk length (NC*CL == Tt)

// ---------------------------------------------------------------------------
// Kernel 1: featurize -> featraw (M, 225)
// ---------------------------------------------------------------------------
__global__ __launch_bounds__(256) void feat_kernel(const float* __restrict__ x,
                                                   float* __restrict__ featraw) {
    int r = blockIdx.x;          // 0..8191 (b*T+t)
    int c = threadIdx.x;         // 0..255, valid < 225
    if (c >= 225) return;
    int t = r & (Tt - 1);
    int j = c / 9;
    int cc = c - j * 9;
    int comp = cc % 3;
    int kind = cc / 3;

    auto POS = [&](int dt) -> float {
        const float* p = x + (long)(r - dt) * Jj * 3;
        return p[j * 3 + comp] - p[comp];
    };

    float v;
    if (kind == 0) {
        v = POS(0);
    } else if (kind == 1) {
        v = (t >= 1) ? (POS(0) - POS(1)) : 0.f;
    } else {
        if (t >= 2)      v = POS(0) - 2.f * POS(1) + POS(2);
        else if (t == 1) v = POS(0) - POS(1);
        else             v = 0.f;
    }
    featraw[(long)r * 225 + c] = v;
}

// ---------------------------------------------------------------------------
// Generic tiled fp32 GEMM: C[M,N] = epi( A[M,K](lda) @ W[N,K]^T + bias )
// epi: 0=none, 1=+bias, 2=+bias then softplus, 3=+resid
// ---------------------------------------------------------------------------
#define BM 64
#define BN 64
#define BK 16

__global__ __launch_bounds__(256) void gemm_kernel(
    const float* __restrict__ A, int lda,
    const float* __restrict__ W,
    const float* __restrict__ bias,
    const float* __restrict__ resid, int ldr,
    float* __restrict__ C, int ldc,
    int M, int N, int K, int epi)
{
    __shared__ float As[BK][BM + 1];
    __shared__ float Ws[BK][BN + 1];
    int tid = threadIdx.x;
    int m0 = blockIdx.y * BM;
    int n0 = blockIdx.x * BN;
    int tx = tid & 15, ty = tid >> 4;
    int lr = tid >> 2;          // 0..63
    int lk = (tid & 3) * 4;     // 0,4,8,12
    float acc[4][4] = {};

    for (int k0 = 0; k0 < K; k0 += BK) {
        int gm = m0 + lr;
        int gn = n0 + lr;
#pragma unroll
        for (int i = 0; i < 4; i++) {
            int gk = k0 + lk + i;
            As[lk + i][lr] = (gm < M && gk < K) ? A[(long)gm * lda + gk] : 0.f;
            Ws[lk + i][lr] = (gn < N && gk < K) ? W[(long)gn * K + gk] : 0.f;
        }
        __syncthreads();
#pragma unroll
        for (int kk = 0; kk < BK; kk++) {
            float a[4], w[4];
#pragma unroll
            for (int i = 0; i < 4; i++) a[i] = As[kk][ty * 4 + i];
#pragma unroll
            for (int j = 0; j < 4; j++) w[j] = Ws[kk][tx * 4 + j];
#pragma unroll
            for (int i = 0; i < 4; i++)
#pragma unroll
                for (int j = 0; j < 4; j++)
                    acc[i][j] += a[i] * w[j];
        }
        __syncthreads();
    }

#pragma unroll
    for (int i = 0; i < 4; i++) {
        int gm = m0 + ty * 4 + i;
        if (gm >= M) continue;
#pragma unroll
        for (int j = 0; j < 4; j++) {
            int gn = n0 + tx * 4 + j;
            if (gn >= N) continue;
            float v = acc[i][j];
            if (epi == 1 || epi == 2) v += bias[gn];
            if (epi == 2) v = fmaxf(v, 0.f) + log1pf(expf(-fabsf(v)));
            if (epi == 3) v += resid[(long)gm * ldr + gn];
            C[(long)gm * ldc + gn] = v;
        }
    }
}

// ---------------------------------------------------------------------------
// LayerNorm over D=256 per row
// ---------------------------------------------------------------------------
__global__ __launch_bounds__(256) void ln_kernel(const float* __restrict__ x,
                                                 const float* __restrict__ g,
                                                 const float* __restrict__ b,
                                                 float* __restrict__ out) {
    __shared__ float red[256];
    long r = blockIdx.x;
    int d = threadIdx.x;
    float v = x[r * 256 + d];
    red[d] = v;
    __syncthreads();
    for (int s = 128; s > 0; s >>= 1) {
        if (d < s) red[d] += red[d + s];
        __syncthreads();
    }
    float mu = red[0] * (1.f / 256.f);
    __syncthreads();
    float dv = v - mu;
    red[d] = dv * dv;
    __syncthreads();
    for (int s = 128; s > 0; s >>= 1) {
        if (d < s) red[d] += red[d + s];
        __syncthreads();
    }
    float var = red[0] * (1.f / 256.f);
    out[r * 256 + d] = dv * rsqrtf(var + 1e-5f) * g[d] + b[d];
}

// ---------------------------------------------------------------------------
// Causal depthwise conv (k=4) + SiLU
// ---------------------------------------------------------------------------
__global__ __launch_bounds__(256) void conv_silu_kernel(const float* __restrict__ xz,
                                                        const float* __restrict__ cw,
                                                        const float* __restrict__ cb,
                                                        float* __restrict__ xm) {
    int r = blockIdx.x;                      // 0..8191
    int d = blockIdx.y * 256 + threadIdx.x;  // 0..511
    int t = r & (Tt - 1);
    float w0 = cw[d * 4 + 0], w1 = cw[d * 4 + 1], w2 = cw[d * 4 + 2], w3 = cw[d * 4 + 3];
    float acc = cb[d];
    acc += w3 * xz[(long)r * 1024 + d];
    if (t >= 1) acc += w2 * xz[(long)(r - 1) * 1024 + d];
    if (t >= 2) acc += w1 * xz[(long)(r - 2) * 1024 + d];
    if (t >= 3) acc += w0 * xz[(long)(r - 3) * 1024 + d];
    float s = acc / (1.f + expf(-acc));
    xm[(long)r * 512 + d] = s;
}

// ---------------------------------------------------------------------------
// Chunked selective scan.
// Pass 1: per chunk (len CL) compute local end-state S (h0=0) and sum(delta).
//   chunk decay product over the chunk is exp(A * sum(delta)) exactly.
// Combine: sequential over NC chunks per (b,d,n); rewrites chunkS in-place
//   with the chunk ENTRY state H.
// Pass 2: replay each chunk from H, emit y = (C.h + u*D) * silu(res).
// ---------------------------------------------------------------------------
__global__ __launch_bounds__(64) void scan_p1(const float* __restrict__ delta,
                                              const float* __restrict__ u_,
                                              const float* __restrict__ dbl,
                                              const float* __restrict__ A_log,
                                              float* __restrict__ chunkS,
                                              float* __restrict__ sumdelta) {
    int b = blockIdx.x;                      // 0..7
    int c = blockIdx.y;                      // 0..NC-1
    int d = blockIdx.z * 64 + threadIdx.x;   // 0..511
    float Arow[16];
#pragma unroll
    for (int n = 0; n < 16; n++) Arow[n] = -expf(A_log[d * 16 + n]);
    float S[16];
#pragma unroll
    for (int n = 0; n < 16; n++) S[n] = 0.f;
    float sd = 0.f;
    long r0 = (long)b * Tt + (long)c * CL;

    for (int t = 0; t < CL; t++) {
        long r = r0 + t;
        float dl = delta[r * 512 + d];
        float u  = u_[r * 512 + d];
        float du = dl * u;
        sd += dl;
        float Bn[16];
        const float4* Bp = (const float4*)(dbl + r * 48 + 16);
#pragma unroll
        for (int q = 0; q < 4; q++) {
            float4 bv = Bp[q];
            Bn[q*4+0] = bv.x; Bn[q*4+1] = bv.y; Bn[q*4+2] = bv.z; Bn[q*4+3] = bv.w;
        }
#pragma unroll
        for (int n = 0; n < 16; n++) {
            float a = expf(dl * Arow[n]);
            S[n] = a * S[n] + du * Bn[n];
        }
    }
    long base = ((long)(b * NC + c) * 16) * 512 + d;
#pragma unroll
    for (int n = 0; n < 16; n++) chunkS[base + (long)n * 512] = S[n];
    sumdelta[(long)(b * NC + c) * 512 + d] = sd;
}

__global__ __launch_bounds__(256) void scan_combine(float* chunkS,
                                                    const float* __restrict__ sumdelta,
                                                    const float* __restrict__ A_log) {
    int idx = blockIdx.x * 256 + threadIdx.x;   // 0..65535
    int d = idx & 511;
    int n = (idx >> 9) & 15;
    int b = idx >> 13;
    float Aval = -expf(A_log[d * 16 + n]);
    float h = 0.f;
    for (int c = 0; c < NC; c++) {
        long si = ((long)(b * NC + c) * 16 + n) * 512 + d;
        float s = chunkS[si];
        float a = expf(Aval * sumdelta[(long)(b * NC + c) * 512 + d]);
        chunkS[si] = h;            // entry state for chunk c
        h = a * h + s;
    }
}

__global__ __launch_bounds__(64) void scan_p2(const float* delta,   // aliases y
                                              const float* __restrict__ u_,
                                              const float* __restrict__ dbl,
                                              const float* __restrict__ xz,
                                              const float* __restrict__ A_log,
                                              const float* __restrict__ Dv,
                                              const float* __restrict__ chunkH,
                                              float* y) {
    int b = blockIdx.x;
    int c = blockIdx.y;
    int d = blockIdx.z * 64 + threadIdx.x;
    float Arow[16];
#pragma unroll
    for (int n = 0; n < 16; n++) Arow[n] = -expf(A_log[d * 16 + n]);
    float Dd = Dv[d];
    float h[16];
    long base = ((long)(b * NC + c) * 16) * 512 + d;
#pragma unroll
    for (int n = 0; n < 16; n++) h[n] = chunkH[base + (long)n * 512];
    long r0 = (long)b * Tt + (long)c * CL;

    for (int t = 0; t < CL; t++) {
        long r = r0 + t;
        float dl  = delta[r * 512 + d];
        float u   = u_[r * 512 + d];
        float res = xz[r * 1024 + 512 + d];
        float du  = dl * u;
        float Bn[16], Cn[16];
        const float4* Bp = (const float4*)(dbl + r * 48 + 16);
        const float4* Cp = (const float4*)(dbl + r * 48 + 32);
#pragma unroll
        for (int q = 0; q < 4; q++) {
            float4 bv = Bp[q];
            float4 cv = Cp[q];
            Bn[q*4+0] = bv.x; Bn[q*4+1] = bv.y; Bn[q*4+2] = bv.z; Bn[q*4+3] = bv.w;
            Cn[q*4+0] = cv.x; Cn[q*4+1] = cv.y; Cn[q*4+2] = cv.z; Cn[q*4+3] = cv.w;
        }
        float ysum = 0.f;
#pragma unroll
        for (int n = 0; n < 16; n++) {
            float a = expf(dl * Arow[n]);
            h[n] = a * h[n] + du * Bn[n];
            ysum += h[n] * Cn[n];
        }
        float yy = ysum + u * Dd;
        float sres = res / (1.f + expf(-res));
        y[r * 512 + d] = yy * sres;
    }
}

// ---------------------------------------------------------------------------
// Pool + head
// ---------------------------------------------------------------------------
__global__ __launch_bounds__(256) void pool_kernel(const float* __restrict__ fn,
                                                   float* __restrict__ pooled) {
    int b = blockIdx.x;
    int q = blockIdx.y;   // 16 chunks of 64 rows
    int d = threadIdx.x;
    float s = 0.f;
    for (int i = 0; i < 64; i++) {
        long t = q * 64 + i;
        s += fn[((long)b * Tt + t) * 256 + d];
    }
    atomicAdd(&pooled[b * 256 + d], s);
}

__global__ __launch_bounds__(64) void head_kernel(const float* __restrict__ pooled,
                                                  const float* __restrict__ fw,
                                                  const float* __restrict__ fb,
                                                  float* __restrict__ out) {
    int b = blockIdx.x;
    int n = threadIdx.x;
    if (n >= N_CLASSES) return;
    float s = 0.f;
    for (int k = 0; k < 256; k++) s += pooled[b * 256 + k] * fw[n * 256 + k];
    out[b * N_CLASSES + n] = s * (1.f / (float)Tt) + fb[n];
}

// ---------------------------------------------------------------------------
extern "C" void kernel_launch(void* const* d_in, const int* in_sizes, int n_in,
                              void* d_out, int out_size, void* d_ws, size_t ws_size,
                              hipStream_t stream) {
    const float* x         = (const float*)d_in[0];
    const float* embed_w   = (const float*)d_in[1];
    const float* embed_b   = (const float*)d_in[2];
    const float* pre_g     = (const float*)d_in[3];
    const float* pre_b     = (const float*)d_in[4];
    const float* in_proj_w = (const float*)d_in[5];
    const float* conv_w    = (const float*)d_in[6];
    const float* conv_b    = (const float*)d_in[7];
    const float* x_proj_w  = (const float*)d_in[8];
    const float* dt_proj_w = (const float*)d_in[9];
    const float* dt_proj_b = (const float*)d_in[10];
    const float* A_log     = (const float*)d_in[11];
    const float* Dv        = (const float*)d_in[12];
    const float* out_proj_w= (const float*)d_in[13];
    const float* post_g    = (const float*)d_in[14];
    const float* post_b    = (const float*)d_in[15];
    const float* fine_w    = (const float*)d_in[16];
    const float* fine_b    = (const float*)d_in[17];
    float* out = (float*)d_out;
    float* ws  = (float*)d_ws;

    // workspace layout (floats)
    float* featraw = ws;                        // 1,843,200  (reused as dbl)
    float* feat    = ws + 1843200;              // 2,097,152
    float* hn      = feat + 2097152;            // 2,097,152  (dead during scan -> chunkS; then post-LN out)
    float* xz      = hn + 2097152;              // 8,388,608
    float* xm      = xz + 8388608;              // 4,194,304
    float* delta   = xm + 4194304;              // 4,194,304  (scan writes y in-place)
    float* pooled  = delta + 4194304;           // 2,048
    float* sumdelta= pooled + 2048;             // 131,072
    float* dbl     = featraw;                   // (M,48) fits in dead featraw
    float* chunkS  = hn;                        // 8*NC*16*512 = 2,097,152 (in-place -> H)

    // 1. featurize
    feat_kernel<<<dim3(Mrows), dim3(256), 0, stream>>>(x, featraw);

    // 2. embed: feat = featraw @ embed_w^T + embed_b   (K=225, N=256)
    gemm_kernel<<<dim3(4, 128), dim3(256), 0, stream>>>(
        featraw, 225, embed_w, embed_b, nullptr, 0, feat, 256, Mrows, 256, 225, 1);

    // 3. pre layernorm -> hn
    ln_kernel<<<dim3(Mrows), dim3(256), 0, stream>>>(feat, pre_g, pre_b, hn);

    // 4. in_proj: xz = hn @ in_proj_w^T  (K=256, N=1024)
    gemm_kernel<<<dim3(16, 128), dim3(256), 0, stream>>>(
        hn, 256, in_proj_w, nullptr, nullptr, 0, xz, 1024, Mrows, 1024, 256, 0);

    // 5. conv + silu -> xm
    conv_silu_kernel<<<dim3(Mrows, 2), dim3(256), 0, stream>>>(xz, conv_w, conv_b, xm);

    // 6. x_proj: dbl = xm @ x_proj_w^T  (K=512, N=48)
    gemm_kernel<<<dim3(1, 128), dim3(256), 0, stream>>>(
        xm, 512, x_proj_w, nullptr, nullptr, 0, dbl, 48, Mrows, 48, 512, 0);

    // 7. dt_proj + softplus: delta = softplus(dbl[:, :16] @ dt_proj_w^T + b)
    gemm_kernel<<<dim3(8, 128), dim3(256), 0, stream>>>(
        dbl, 48, dt_proj_w, dt_proj_b, nullptr, 0, delta, 512, Mrows, 512, 16, 2);

    // 8. chunked selective scan (y written in-place over delta)
    scan_p1<<<dim3(Bb, NC, 8), dim3(64), 0, stream>>>(delta, xm, dbl, A_log, chunkS, sumdelta);
    scan_combine<<<dim3(256), dim3(256), 0, stream>>>(chunkS, sumdelta, A_log);
    scan_p2<<<dim3(Bb, NC, 8), dim3(64), 0, stream>>>(delta, xm, dbl, xz, A_log, Dv, chunkS, delta);

    // 9. out_proj + residual: feat = feat + y @ out_proj_w^T  (K=512, N=256)
    gemm_kernel<<<dim3(4, 128), dim3(256), 0, stream>>>(
        delta, 512, out_proj_w, nullptr, feat, 256, feat, 256, Mrows, 256, 512, 3);

    // 10. post layernorm -> hn (reuse)
    ln_kernel<<<dim3(Mrows), dim3(256), 0, stream>>>(feat, post_g, post_b, hn);

    // 11. pool
    hipMemsetAsync(pooled, 0, Bb * 256 * sizeof(float), stream);
    pool_kernel<<<dim3(Bb, 16), dim3(256), 0, stream>>>(hn, pooled);

    // 12. head
    head_kernel<<<dim3(Bb), dim3(64), 0, stream>>>(pooled, fine_w, fine_b, out);
}

// Round 3
// 432.446 us; speedup vs baseline: 3.3124x; 1.5068x over previous
//
#include <hip/hip_runtime.h>
#include <hip/hip_bf16.h>
#include <math.h>

// Problem constants
#define Bb 8
#define Tt 1024
#define Jj 25
#define D_MODEL 256
#define D_STATE 16
#define D_CONV 4
#define D_INNER 512
#define DT_RANK 16
#define N_CLASSES 60
#define Mrows (Bb*Tt)   // 8192
#define NC 32           // scan chunks
#define CL 32           // chunk length (NC*CL == Tt)

// ---------------------------------------------------------------------------
// Kernel 1: featurize -> featraw (M, 225)
// ---------------------------------------------------------------------------
__global__ __launch_bounds__(256) void feat_kernel(const float* __restrict__ x,
                                                   float* __restrict__ featraw) {
    int r = blockIdx.x;          // 0..8191 (b*T+t)
    int c = threadIdx.x;         // 0..255, valid < 225
    if (c >= 225) return;
    int t = r & (Tt - 1);
    int j = c / 9;
    int cc = c - j * 9;
    int comp = cc % 3;
    int kind = cc / 3;

    auto POS = [&](int dt) -> float {
        const float* p = x + (long)(r - dt) * Jj * 3;
        return p[j * 3 + comp] - p[comp];
    };

    float v;
    if (kind == 0) {
        v = POS(0);
    } else if (kind == 1) {
        v = (t >= 1) ? (POS(0) - POS(1)) : 0.f;
    } else {
        if (t >= 2)      v = POS(0) - 2.f * POS(1) + POS(2);
        else if (t == 1) v = POS(0) - POS(1);
        else             v = 0.f;
    }
    featraw[(long)r * 225 + c] = v;
}

// ---------------------------------------------------------------------------
// Tiled fp32 GEMM: C[M,N] = epi( A[M,K](lda) @ W[N,K]^T + bias )
// epi: 0=none, 1=+bias, 2=+bias then softplus, 3=+resid
// k-major LDS tiles (stride BM+4 keeps b128 alignment, kills pow2 banking).
// BMt=BNt=128: 8x8/thread in 2x2 split fragments. BMt=BNt=64: 4x4/thread.
// ---------------------------------------------------------------------------
template<int BMt, int BNt>
__global__ __launch_bounds__(256) void gemm_tiled(
    const float* __restrict__ A, int lda,
    const float* __restrict__ W,
    const float* __restrict__ bias,
    const float* __restrict__ resid, int ldr,
    float* __restrict__ C, int ldc,
    int M, int N, int K, int epi)
{
    constexpr int HM = BMt / 64;   // 1 or 2
    constexpr int HN = BNt / 64;
    __shared__ float As[16][BMt + 4];
    __shared__ float Ws[16][BNt + 4];
    int tid = threadIdx.x;
    int m0 = blockIdx.y * BMt;
    int n0 = blockIdx.x * BNt;
    int tx = tid & 15, ty = tid >> 4;
    float acc[HM * 4][HN * 4] = {};

    for (int k0 = 0; k0 < K; k0 += 16) {
        // stage A tile (BMt x 16), k-major in LDS
#pragma unroll
        for (int it = 0; it < HM; it++) {
            int idx = tid + it * 256;
            int kq = idx & 3;
            int m  = idx >> 2;
            int gm = m0 + m;
            int gk = k0 + kq * 4;
            float4 v = make_float4(0.f, 0.f, 0.f, 0.f);
            if (gm < M) {
                if (gk + 3 < K) {
                    v = *(const float4*)(A + (long)gm * lda + gk);
                } else {
                    float tmp[4] = {0.f, 0.f, 0.f, 0.f};
#pragma unroll
                    for (int s = 0; s < 4; s++)
                        if (gk + s < K) tmp[s] = A[(long)gm * lda + gk + s];
                    v = make_float4(tmp[0], tmp[1], tmp[2], tmp[3]);
                }
            }
            As[kq * 4 + 0][m] = v.x;
            As[kq * 4 + 1][m] = v.y;
            As[kq * 4 + 2][m] = v.z;
            As[kq * 4 + 3][m] = v.w;
        }
        // stage W tile (BNt x 16), k-major in LDS
#pragma unroll
        for (int it = 0; it < HN; it++) {
            int idx = tid + it * 256;
            int kq = idx & 3;
            int n  = idx >> 2;
            int gn = n0 + n;
            int gk = k0 + kq * 4;
            float4 v = make_float4(0.f, 0.f, 0.f, 0.f);
            if (gn < N) {
                if (gk + 3 < K) {
                    v = *(const float4*)(W + (long)gn * K + gk);
                } else {
                    float tmp[4] = {0.f, 0.f, 0.f, 0.f};
#pragma unroll
                    for (int s = 0; s < 4; s++)
                        if (gk + s < K) tmp[s] = W[(long)gn * K + gk + s];
                    v = make_float4(tmp[0], tmp[1], tmp[2], tmp[3]);
                }
            }
            Ws[kq * 4 + 0][n] = v.x;
            Ws[kq * 4 + 1][n] = v.y;
            Ws[kq * 4 + 2][n] = v.z;
            Ws[kq * 4 + 3][n] = v.w;
        }
        __syncthreads();
#pragma unroll
        for (int kk = 0; kk < 16; kk++) {
            float a[HM * 4], w[HN * 4];
#pragma unroll
            for (int h = 0; h < HM; h++) {
                float4 v = *(const float4*)&As[kk][h * 64 + ty * 4];
                a[h * 4 + 0] = v.x; a[h * 4 + 1] = v.y;
                a[h * 4 + 2] = v.z; a[h * 4 + 3] = v.w;
            }
#pragma unroll
            for (int h = 0; h < HN; h++) {
                float4 v = *(const float4*)&Ws[kk][h * 64 + tx * 4];
                w[h * 4 + 0] = v.x; w[h * 4 + 1] = v.y;
                w[h * 4 + 2] = v.z; w[h * 4 + 3] = v.w;
            }
#pragma unroll
            for (int i = 0; i < HM * 4; i++)
#pragma unroll
                for (int j = 0; j < HN * 4; j++)
                    acc[i][j] += a[i] * w[j];
        }
        __syncthreads();
    }

    // epilogue: float4 stores
#pragma unroll
    for (int h = 0; h < HM; h++) {
#pragma unroll
        for (int i = 0; i < 4; i++) {
            int gm = m0 + h * 64 + ty * 4 + i;
            if (gm >= M) continue;
#pragma unroll
            for (int hn = 0; hn < HN; hn++) {
                int gn0 = n0 + hn * 64 + tx * 4;
                if (gn0 >= N) continue;
                float vv[4];
#pragma unroll
                for (int j = 0; j < 4; j++) {
                    int gn = gn0 + j;
                    float v = acc[h * 4 + i][hn * 4 + j];
                    if (epi == 1 || epi == 2) v += bias[gn];
                    if (epi == 2) v = fmaxf(v, 0.f) + log1pf(expf(-fabsf(v)));
                    if (epi == 3) v += resid[(long)gm * ldr + gn];
                    vv[j] = v;
                }
                *(float4*)(C + (long)gm * ldc + gn0) = make_float4(vv[0], vv[1], vv[2], vv[3]);
            }
        }
    }
}

// ---------------------------------------------------------------------------
// LayerNorm over D=256 per row
// ---------------------------------------------------------------------------
__global__ __launch_bounds__(256) void ln_kernel(const float* __restrict__ x,
                                                 const float* __restrict__ g,
                                                 const float* __restrict__ b,
                                                 float* __restrict__ out) {
    __shared__ float red[256];
    long r = blockIdx.x;
    int d = threadIdx.x;
    float v = x[r * 256 + d];
    red[d] = v;
    __syncthreads();
    for (int s = 128; s > 0; s >>= 1) {
        if (d < s) red[d] += red[d + s];
        __syncthreads();
    }
    float mu = red[0] * (1.f / 256.f);
    __syncthreads();
    float dv = v - mu;
    red[d] = dv * dv;
    __syncthreads();
    for (int s = 128; s > 0; s >>= 1) {
        if (d < s) red[d] += red[d + s];
        __syncthreads();
    }
    float var = red[0] * (1.f / 256.f);
    out[r * 256 + d] = dv * rsqrtf(var + 1e-5f) * g[d] + b[d];
}

// ---------------------------------------------------------------------------
// Causal depthwise conv (k=4) + SiLU
// ---------------------------------------------------------------------------
__global__ __launch_bounds__(256) void conv_silu_kernel(const float* __restrict__ xz,
                                                        const float* __restrict__ cw,
                                                        const float* __restrict__ cb,
                                                        float* __restrict__ xm) {
    int r = blockIdx.x;                      // 0..8191
    int d = blockIdx.y * 256 + threadIdx.x;  // 0..511
    int t = r & (Tt - 1);
    float w0 = cw[d * 4 + 0], w1 = cw[d * 4 + 1], w2 = cw[d * 4 + 2], w3 = cw[d * 4 + 3];
    float acc = cb[d];
    acc += w3 * xz[(long)r * 1024 + d];
    if (t >= 1) acc += w2 * xz[(long)(r - 1) * 1024 + d];
    if (t >= 2) acc += w1 * xz[(long)(r - 2) * 1024 + d];
    if (t >= 3) acc += w0 * xz[(long)(r - 3) * 1024 + d];
    float s = acc / (1.f + expf(-acc));
    xm[(long)r * 512 + d] = s;
}

// ---------------------------------------------------------------------------
// Chunked selective scan (3 passes).
// ---------------------------------------------------------------------------
__global__ __launch_bounds__(64) void scan_p1(const float* __restrict__ delta,
                                              const float* __restrict__ u_,
                                              const float* __restrict__ dbl,
                                              const float* __restrict__ A_log,
                                              float* __restrict__ chunkS,
                                              float* __restrict__ sumdelta) {
    int b = blockIdx.x;                      // 0..7
    int c = blockIdx.y;                      // 0..NC-1
    int d = blockIdx.z * 64 + threadIdx.x;   // 0..511
    float Arow[16];
#pragma unroll
    for (int n = 0; n < 16; n++) Arow[n] = -expf(A_log[d * 16 + n]);
    float S[16];
#pragma unroll
    for (int n = 0; n < 16; n++) S[n] = 0.f;
    float sd = 0.f;
    long r0 = (long)b * Tt + (long)c * CL;

    for (int t = 0; t < CL; t++) {
        long r = r0 + t;
        float dl = delta[r * 512 + d];
        float u  = u_[r * 512 + d];
        float du = dl * u;
        sd += dl;
        float Bn[16];
        const float4* Bp = (const float4*)(dbl + r * 48 + 16);
#pragma unroll
        for (int q = 0; q < 4; q++) {
            float4 bv = Bp[q];
            Bn[q*4+0] = bv.x; Bn[q*4+1] = bv.y; Bn[q*4+2] = bv.z; Bn[q*4+3] = bv.w;
        }
#pragma unroll
        for (int n = 0; n < 16; n++) {
            float a = expf(dl * Arow[n]);
            S[n] = a * S[n] + du * Bn[n];
        }
    }
    long base = ((long)(b * NC + c) * 16) * 512 + d;
#pragma unroll
    for (int n = 0; n < 16; n++) chunkS[base + (long)n * 512] = S[n];
    sumdelta[(long)(b * NC + c) * 512 + d] = sd;
}

__global__ __launch_bounds__(256) void scan_combine(float* chunkS,
                                                    const float* __restrict__ sumdelta,
                                                    const float* __restrict__ A_log) {
    int idx = blockIdx.x * 256 + threadIdx.x;   // 0..65535
    int d = idx & 511;
    int n = (idx >> 9) & 15;
    int b = idx >> 13;
    float Aval = -expf(A_log[d * 16 + n]);
    float h = 0.f;
    for (int c = 0; c < NC; c++) {
        long si = ((long)(b * NC + c) * 16 + n) * 512 + d;
        float s = chunkS[si];
        float a = expf(Aval * sumdelta[(long)(b * NC + c) * 512 + d]);
        chunkS[si] = h;            // entry state for chunk c
        h = a * h + s;
    }
}

__global__ __launch_bounds__(64) void scan_p2(const float* delta,   // aliases y
                                              const float* __restrict__ u_,
                                              const float* __restrict__ dbl,
                                              const float* __restrict__ xz,
                                              const float* __restrict__ A_log,
                                              const float* __restrict__ Dv,
                                              const float* __restrict__ chunkH,
                                              float* y) {
    int b = blockIdx.x;
    int c = blockIdx.y;
    int d = blockIdx.z * 64 + threadIdx.x;
    float Arow[16];
#pragma unroll
    for (int n = 0; n < 16; n++) Arow[n] = -expf(A_log[d * 16 + n]);
    float Dd = Dv[d];
    float h[16];
    long base = ((long)(b * NC + c) * 16) * 512 + d;
#pragma unroll
    for (int n = 0; n < 16; n++) h[n] = chunkH[base + (long)n * 512];
    long r0 = (long)b * Tt + (long)c * CL;

    for (int t = 0; t < CL; t++) {
        long r = r0 + t;
        float dl  = delta[r * 512 + d];
        float u   = u_[r * 512 + d];
        float res = xz[r * 1024 + 512 + d];
        float du  = dl * u;
        float Bn[16], Cn[16];
        const float4* Bp = (const float4*)(dbl + r * 48 + 16);
        const float4* Cp = (const float4*)(dbl + r * 48 + 32);
#pragma unroll
        for (int q = 0; q < 4; q++) {
            float4 bv = Bp[q];
            float4 cv = Cp[q];
            Bn[q*4+0] = bv.x; Bn[q*4+1] = bv.y; Bn[q*4+2] = bv.z; Bn[q*4+3] = bv.w;
            Cn[q*4+0] = cv.x; Cn[q*4+1] = cv.y; Cn[q*4+2] = cv.z; Cn[q*4+3] = cv.w;
        }
        float ysum = 0.f;
#pragma unroll
        for (int n = 0; n < 16; n++) {
            float a = expf(dl * Arow[n]);
            h[n] = a * h[n] + du * Bn[n];
            ysum += h[n] * Cn[n];
        }
        float yy = ysum + u * Dd;
        float sres = res / (1.f + expf(-res));
        y[r * 512 + d] = yy * sres;
    }
}

// ---------------------------------------------------------------------------
// Pool + head
// ---------------------------------------------------------------------------
__global__ __launch_bounds__(256) void pool_kernel(const float* __restrict__ fn,
                                                   float* __restrict__ pooled) {
    int b = blockIdx.x;
    int q = blockIdx.y;   // 16 chunks of 64 rows
    int d = threadIdx.x;
    float s = 0.f;
    for (int i = 0; i < 64; i++) {
        long t = q * 64 + i;
        s += fn[((long)b * Tt + t) * 256 + d];
    }
    atomicAdd(&pooled[b * 256 + d], s);
}

__global__ __launch_bounds__(64) void head_kernel(const float* __restrict__ pooled,
                                                  const float* __restrict__ fw,
                                                  const float* __restrict__ fb,
                                                  float* __restrict__ out) {
    int b = blockIdx.x;
    int n = threadIdx.x;
    if (n >= N_CLASSES) return;
    float s = 0.f;
    for (int k = 0; k < 256; k++) s += pooled[b * 256 + k] * fw[n * 256 + k];
    out[b * N_CLASSES + n] = s * (1.f / (float)Tt) + fb[n];
}

// ---------------------------------------------------------------------------
extern "C" void kernel_launch(void* const* d_in, const int* in_sizes, int n_in,
                              void* d_out, int out_size, void* d_ws, size_t ws_size,
                              hipStream_t stream) {
    const float* x         = (const float*)d_in[0];
    const float* embed_w   = (const float*)d_in[1];
    const float* embed_b   = (const float*)d_in[2];
    const float* pre_g     = (const float*)d_in[3];
    const float* pre_b     = (const float*)d_in[4];
    const float* in_proj_w = (const float*)d_in[5];
    const float* conv_w    = (const float*)d_in[6];
    const float* conv_b    = (const float*)d_in[7];
    const float* x_proj_w  = (const float*)d_in[8];
    const float* dt_proj_w = (const float*)d_in[9];
    const float* dt_proj_b = (const float*)d_in[10];
    const float* A_log     = (const float*)d_in[11];
    const float* Dv        = (const float*)d_in[12];
    const float* out_proj_w= (const float*)d_in[13];
    const float* post_g    = (const float*)d_in[14];
    const float* post_b    = (const float*)d_in[15];
    const float* fine_w    = (const float*)d_in[16];
    const float* fine_b    = (const float*)d_in[17];
    float* out = (float*)d_out;
    float* ws  = (float*)d_ws;

    // workspace layout (floats)
    float* featraw = ws;                        // 1,843,200  (reused as dbl)
    float* feat    = ws + 1843200;              // 2,097,152
    float* hn      = feat + 2097152;            // 2,097,152  (dead during scan -> chunkS; then post-LN out)
    float* xz      = hn + 2097152;              // 8,388,608
    float* xm      = xz + 8388608;              // 4,194,304
    float* delta   = xm + 4194304;              // 4,194,304  (scan writes y in-place)
    float* pooled  = delta + 4194304;           // 2,048
    float* sumdelta= pooled + 2048;             // 131,072
    float* dbl     = featraw;                   // (M,48) fits in dead featraw
    float* chunkS  = hn;                        // 8*NC*16*512 = 2,097,152 (in-place -> H)

    // 1. featurize
    feat_kernel<<<dim3(Mrows), dim3(256), 0, stream>>>(x, featraw);

    // 2. embed: feat = featraw @ embed_w^T + embed_b   (K=225, N=256)
    gemm_tiled<64,64><<<dim3(4, 128), dim3(256), 0, stream>>>(
        featraw, 225, embed_w, embed_b, nullptr, 0, feat, 256, Mrows, 256, 225, 1);

    // 3. pre layernorm -> hn
    ln_kernel<<<dim3(Mrows), dim3(256), 0, stream>>>(feat, pre_g, pre_b, hn);

    // 4. in_proj: xz = hn @ in_proj_w^T  (K=256, N=1024)
    gemm_tiled<128,128><<<dim3(8, 64), dim3(256), 0, stream>>>(
        hn, 256, in_proj_w, nullptr, nullptr, 0, xz, 1024, Mrows, 1024, 256, 0);

    // 5. conv + silu -> xm
    conv_silu_kernel<<<dim3(Mrows, 2), dim3(256), 0, stream>>>(xz, conv_w, conv_b, xm);

    // 6. x_proj: dbl = xm @ x_proj_w^T  (K=512, N=48)
    gemm_tiled<64,64><<<dim3(1, 128), dim3(256), 0, stream>>>(
        xm, 512, x_proj_w, nullptr, nullptr, 0, dbl, 48, Mrows, 48, 512, 0);

    // 7. dt_proj + softplus: delta = softplus(dbl[:, :16] @ dt_proj_w^T + b)
    gemm_tiled<64,64><<<dim3(8, 128), dim3(256), 0, stream>>>(
        dbl, 48, dt_proj_w, dt_proj_b, nullptr, 0, delta, 512, Mrows, 512, 16, 2);

    // 8. chunked selective scan (y written in-place over delta)
    scan_p1<<<dim3(Bb, NC, 8), dim3(64), 0, stream>>>(delta, xm, dbl, A_log, chunkS, sumdelta);
    scan_combine<<<dim3(256), dim3(256), 0, stream>>>(chunkS, sumdelta, A_log);
    scan_p2<<<dim3(Bb, NC, 8), dim3(64), 0, stream>>>(delta, xm, dbl, xz, A_log, Dv, chunkS, delta);

    // 9. out_proj + residual: feat = feat + y @ out_proj_w^T  (K=512, N=256)
    gemm_tiled<64,64><<<dim3(4, 128), dim3(256), 0, stream>>>(
        delta, 512, out_proj_w, nullptr, feat, 256, feat, 256, Mrows, 256, 512, 3);

    // 10. post layernorm -> hn (reuse)
    ln_kernel<<<dim3(Mrows), dim3(256), 0, stream>>>(feat, post_g, post_b, hn);

    // 11. pool
    hipMemsetAsync(pooled, 0, Bb * 256 * sizeof(float), stream);
    pool_kernel<<<dim3(Bb, 16), dim3(256), 0, stream>>>(hn, pooled);

    // 12. head
    head_kernel<<<dim3(Bb), dim3(64), 0, stream>>>(pooled, fine_w, fine_b, out);
}

// Round 4
// 357.567 us; speedup vs baseline: 4.0061x; 1.2094x over previous
//
#include <hip/hip_runtime.h>
#include <hip/hip_bf16.h>
#include <math.h>

// Problem constants
#define Bb 8
#define Tt 1024
#define Jj 25
#define D_MODEL 256
#define D_STATE 16
#define D_CONV 4
#define D_INNER 512
#define DT_RANK 16
#define N_CLASSES 60
#define Mrows (Bb*Tt)   // 8192
#define NC 32           // scan chunks
#define CL 32           // chunk length (NC*CL == Tt)

typedef unsigned short u16;
using bf16x8 = __attribute__((ext_vector_type(8))) __bf16;
using f32x4  = __attribute__((ext_vector_type(4))) float;

// ---- bf16 split helpers (manual RNE, no header dependency) ----------------
__device__ inline u16 f2bf(float x) {
    unsigned u = __float_as_uint(x);
    unsigned r = (u + 0x7fffu + ((u >> 16) & 1u)) >> 16;
    return (u16)r;
}
__device__ inline float bf2f(u16 h) { return __uint_as_float((unsigned)h << 16); }
__device__ inline void split2(float x, u16& h, u16& l) {
    h = f2bf(x);
    l = f2bf(x - bf2f(h));
}

__device__ inline f32x4 mfma3(bf16x8 ah, bf16x8 al, bf16x8 bh, bf16x8 bl, f32x4 c) {
    c = __builtin_amdgcn_mfma_f32_16x16x32_bf16(al, bh, c, 0, 0, 0);
    c = __builtin_amdgcn_mfma_f32_16x16x32_bf16(ah, bl, c, 0, 0, 0);
    c = __builtin_amdgcn_mfma_f32_16x16x32_bf16(ah, bh, c, 0, 0, 0);
    return c;
}

// ---------------------------------------------------------------------------
// featurize -> featbf hi/lo (M, 256) bf16, zero-padded K 225->256
// ---------------------------------------------------------------------------
__global__ __launch_bounds__(256) void feat_kernel(const float* __restrict__ x,
                                                   u16* __restrict__ fh,
                                                   u16* __restrict__ fl) {
    int r = blockIdx.x;          // 0..8191
    int c = threadIdx.x;         // 0..255
    float v = 0.f;
    if (c < 225) {
        int t = r & (Tt - 1);
        int j = c / 9;
        int cc = c - j * 9;
        int comp = cc % 3;
        int kind = cc / 3;
        auto POS = [&](int dt) -> float {
            const float* p = x + (long)(r - dt) * Jj * 3;
            return p[j * 3 + comp] - p[comp];
        };
        if (kind == 0) {
            v = POS(0);
        } else if (kind == 1) {
            v = (t >= 1) ? (POS(0) - POS(1)) : 0.f;
        } else {
            if (t >= 2)      v = POS(0) - 2.f * POS(1) + POS(2);
            else if (t == 1) v = POS(0) - POS(1);
            else             v = 0.f;
        }
    }
    u16 h, l;
    split2(v, h, l);
    fh[(long)r * 256 + c] = h;
    fl[(long)r * 256 + c] = l;
}

// ---------------------------------------------------------------------------
// Weight fp32 -> bf16 hi/lo (k-padded). One dispatch for all 4 weights.
// segments: ebw 256x256(K225), ipw 1024x256(K256), xpw 48x512(K512), opw 256x512(K512)
// ---------------------------------------------------------------------------
__global__ __launch_bounds__(256) void wcvt_kernel(
    const float* __restrict__ ew, const float* __restrict__ iw,
    const float* __restrict__ xw, const float* __restrict__ ow,
    u16* __restrict__ ebh, u16* __restrict__ ebl,
    u16* __restrict__ iph, u16* __restrict__ ipl,
    u16* __restrict__ xph, u16* __restrict__ xpl,
    u16* __restrict__ oph, u16* __restrict__ opl) {
    int i = blockIdx.x * 256 + threadIdx.x;   // 0..483327
    const float* src; u16 *dh, *dl; int K, kshift, idx;
    if (i < 65536)       { src = ew; dh = ebh; dl = ebl; K = 225; kshift = 8; idx = i; }
    else if (i < 327680) { src = iw; dh = iph; dl = ipl; K = 256; kshift = 8; idx = i - 65536; }
    else if (i < 352256) { src = xw; dh = xph; dl = xpl; K = 512; kshift = 9; idx = i - 327680; }
    else                 { src = ow; dh = oph; dl = opl; K = 512; kshift = 9; idx = i - 352256; }
    int n = idx >> kshift;
    int k = idx & ((1 << kshift) - 1);
    float v = (k < K) ? src[(long)n * K + k] : 0.f;
    u16 h, l;
    split2(v, h, l);
    dh[idx] = h;
    dl[idx] = l;
}

// ---------------------------------------------------------------------------
// bf16x3 MFMA GEMM: C[M,N] = epi( A[M,K] @ W[N,K]^T ), A/W as bf16 hi/lo.
// K multiple of 32 (inputs pre-padded). M multiple of BM. N guarded.
// 4 waves in 2x2; wave tile (BM/2)x(BN/2); 16x16x32 MFMA tiles.
// EPI: 0=none, 1=+bias, 3=+resid
// ---------------------------------------------------------------------------
template<int BM, int BN, int EPI>
__global__ __launch_bounds__(256) void gemm_mfma(
    const u16* __restrict__ Ahi, const u16* __restrict__ Alo, int lda,
    const u16* __restrict__ Whi, const u16* __restrict__ Wlo, int ldw,
    const float* __restrict__ bias, const float* __restrict__ resid, int ldr,
    float* __restrict__ C, int ldc, int M, int N, int K)
{
    constexpr int TM = BM / 32;
    constexpr int TN = BN / 32;
    constexpr int SA = 40;   // LDS row stride in u16 (80 B: 16B-aligned, non-pow2)
    __shared__ u16 AsH[BM * SA], AsL[BM * SA];
    __shared__ u16 WsH[BN * SA], WsL[BN * SA];
    int tid = threadIdx.x;
    int m0 = blockIdx.y * BM;
    int n0 = blockIdx.x * BN;
    int lane = tid & 63;
    int wave = tid >> 6;
    int wm = wave >> 1, wn = wave & 1;
    int fr = lane & 15, quad = lane >> 4;
    f32x4 acc[TM][TN] = {};

    for (int k0 = 0; k0 < K; k0 += 32) {
        for (int s = tid; s < BM * 4; s += 256) {
            int row = s >> 2, seg = s & 3;
            long off = (long)(m0 + row) * lda + k0 + seg * 8;
            *(uint4*)&AsH[row * SA + seg * 8] = *(const uint4*)(Ahi + off);
            *(uint4*)&AsL[row * SA + seg * 8] = *(const uint4*)(Alo + off);
        }
        for (int s = tid; s < BN * 4; s += 256) {
            int row = s >> 2, seg = s & 3;
            uint4 vh = make_uint4(0, 0, 0, 0), vl = make_uint4(0, 0, 0, 0);
            if (n0 + row < N) {
                long off = (long)(n0 + row) * ldw + k0 + seg * 8;
                vh = *(const uint4*)(Whi + off);
                vl = *(const uint4*)(Wlo + off);
            }
            *(uint4*)&WsH[row * SA + seg * 8] = vh;
            *(uint4*)&WsL[row * SA + seg * 8] = vl;
        }
        __syncthreads();
        bf16x8 aH[TM], aL[TM], bH[TN], bL[TN];
#pragma unroll
        for (int im = 0; im < TM; im++) {
            int r = wm * (BM / 2) + im * 16 + fr;
            aH[im] = *(const bf16x8*)&AsH[r * SA + quad * 8];
            aL[im] = *(const bf16x8*)&AsL[r * SA + quad * 8];
        }
#pragma unroll
        for (int in = 0; in < TN; in++) {
            int r = wn * (BN / 2) + in * 16 + fr;
            bH[in] = *(const bf16x8*)&WsH[r * SA + quad * 8];
            bL[in] = *(const bf16x8*)&WsL[r * SA + quad * 8];
        }
#pragma unroll
        for (int im = 0; im < TM; im++)
#pragma unroll
            for (int in = 0; in < TN; in++)
                acc[im][in] = mfma3(aH[im], aL[im], bH[in], bL[in], acc[im][in]);
        __syncthreads();
    }
    // epilogue: C/D layout col=lane&15 (n), row=quad*4+reg (m)
#pragma unroll
    for (int im = 0; im < TM; im++) {
#pragma unroll
        for (int in = 0; in < TN; in++) {
#pragma unroll
            for (int reg = 0; reg < 4; reg++) {
                int gm = m0 + wm * (BM / 2) + im * 16 + quad * 4 + reg;
                int gn = n0 + wn * (BN / 2) + in * 16 + fr;
                if (gn >= N) continue;
                float v = acc[im][in][reg];
                if (EPI == 1) v += bias[gn];
                if (EPI == 3) v += resid[(long)gm * ldr + gn];
                C[(long)gm * ldc + gn] = v;
            }
        }
    }
}

// ---------------------------------------------------------------------------
// LayerNorm over D=256 per row. bf=1: write bf16 hi/lo; bf=0: write fp32.
// ---------------------------------------------------------------------------
__global__ __launch_bounds__(256) void ln_kernel(const float* __restrict__ x,
                                                 const float* __restrict__ g,
                                                 const float* __restrict__ b,
                                                 float* outf, u16* outh, u16* outl,
                                                 int bf) {
    __shared__ float red[256];
    long r = blockIdx.x;
    int d = threadIdx.x;
    float v = x[r * 256 + d];
    red[d] = v;
    __syncthreads();
    for (int s = 128; s > 0; s >>= 1) {
        if (d < s) red[d] += red[d + s];
        __syncthreads();
    }
    float mu = red[0] * (1.f / 256.f);
    __syncthreads();
    float dv = v - mu;
    red[d] = dv * dv;
    __syncthreads();
    for (int s = 128; s > 0; s >>= 1) {
        if (d < s) red[d] += red[d + s];
        __syncthreads();
    }
    float var = red[0] * (1.f / 256.f);
    float o = dv * rsqrtf(var + 1e-5f) * g[d] + b[d];
    if (bf) {
        u16 h, l;
        split2(o, h, l);
        outh[r * 256 + d] = h;
        outl[r * 256 + d] = l;
    } else {
        outf[r * 256 + d] = o;
    }
}

// ---------------------------------------------------------------------------
// Causal depthwise conv (k=4) + SiLU -> xm bf16 hi/lo
// ---------------------------------------------------------------------------
__global__ __launch_bounds__(256) void conv_silu_kernel(const float* __restrict__ xz,
                                                        const float* __restrict__ cw,
                                                        const float* __restrict__ cb,
                                                        u16* __restrict__ xmh,
                                                        u16* __restrict__ xml) {
    int r = blockIdx.x;                      // 0..8191
    int d = blockIdx.y * 256 + threadIdx.x;  // 0..511
    int t = r & (Tt - 1);
    float w0 = cw[d * 4 + 0], w1 = cw[d * 4 + 1], w2 = cw[d * 4 + 2], w3 = cw[d * 4 + 3];
    float acc = cb[d];
    acc += w3 * xz[(long)r * 1024 + d];
    if (t >= 1) acc += w2 * xz[(long)(r - 1) * 1024 + d];
    if (t >= 2) acc += w1 * xz[(long)(r - 2) * 1024 + d];
    if (t >= 3) acc += w0 * xz[(long)(r - 3) * 1024 + d];
    float s = acc / (1.f + expf(-acc));
    u16 h, l;
    split2(s, h, l);
    xmh[(long)r * 512 + d] = h;
    xml[(long)r * 512 + d] = l;
}

// ---------------------------------------------------------------------------
// dt_proj + softplus: delta[M,512] = softplus(dbl[:, :16] @ dtw[512,16]^T + b)
// Block = 4 rows; dtw staged in LDS (stride 17 to kill bank conflicts).
// ---------------------------------------------------------------------------
__global__ __launch_bounds__(256) void dtproj_kernel(const float* __restrict__ dbl,
                                                     const float* __restrict__ dtw,
                                                     const float* __restrict__ dtb,
                                                     float* __restrict__ delta) {
    __shared__ float w[512 * 17];
    __shared__ float dr[4][16];
    int tid = threadIdx.x;
    for (int i = tid; i < 8192; i += 256)
        w[(i >> 4) * 17 + (i & 15)] = dtw[i];
    int r0 = blockIdx.x * 4;
    if (tid < 64)
        dr[tid >> 4][tid & 15] = dbl[(long)(r0 + (tid >> 4)) * 48 + (tid & 15)];
    __syncthreads();
#pragma unroll
    for (int rr = 0; rr < 4; rr++) {
#pragma unroll
        for (int jj = 0; jj < 2; jj++) {
            int n = jj * 256 + tid;
            float s = dtb[n];
#pragma unroll
            for (int k = 0; k < 16; k++) s += dr[rr][k] * w[n * 17 + k];
            s = fmaxf(s, 0.f) + log1pf(expf(-fabsf(s)));
            delta[(long)(r0 + rr) * 512 + n] = s;
        }
    }
}

// ---------------------------------------------------------------------------
// Chunked selective scan (3 passes). u reconstructed from bf16 hi+lo.
// ---------------------------------------------------------------------------
__global__ __launch_bounds__(64) void scan_p1(const float* __restrict__ delta,
                                              const u16* __restrict__ xmh,
                                              const u16* __restrict__ xml,
                                              const float* __restrict__ dbl,
                                              const float* __restrict__ A_log,
                                              float* __restrict__ chunkS,
                                              float* __restrict__ sumdelta) {
    int b = blockIdx.x;                      // 0..7
    int c = blockIdx.y;                      // 0..NC-1
    int d = blockIdx.z * 64 + threadIdx.x;   // 0..511
    float Arow[16];
#pragma unroll
    for (int n = 0; n < 16; n++) Arow[n] = -expf(A_log[d * 16 + n]);
    float S[16];
#pragma unroll
    for (int n = 0; n < 16; n++) S[n] = 0.f;
    float sd = 0.f;
    long r0 = (long)b * Tt + (long)c * CL;

    for (int t = 0; t < CL; t++) {
        long r = r0 + t;
        float dl = delta[r * 512 + d];
        float u  = bf2f(xmh[r * 512 + d]) + bf2f(xml[r * 512 + d]);
        float du = dl * u;
        sd += dl;
        float Bn[16];
        const float4* Bp = (const float4*)(dbl + r * 48 + 16);
#pragma unroll
        for (int q = 0; q < 4; q++) {
            float4 bv = Bp[q];
            Bn[q*4+0] = bv.x; Bn[q*4+1] = bv.y; Bn[q*4+2] = bv.z; Bn[q*4+3] = bv.w;
        }
#pragma unroll
        for (int n = 0; n < 16; n++) {
            float a = expf(dl * Arow[n]);
            S[n] = a * S[n] + du * Bn[n];
        }
    }
    long base = ((long)(b * NC + c) * 16) * 512 + d;
#pragma unroll
    for (int n = 0; n < 16; n++) chunkS[base + (long)n * 512] = S[n];
    sumdelta[(long)(b * NC + c) * 512 + d] = sd;
}

__global__ __launch_bounds__(256) void scan_combine(float* chunkS,
                                                    const float* __restrict__ sumdelta,
                                                    const float* __restrict__ A_log) {
    int idx = blockIdx.x * 256 + threadIdx.x;   // 0..65535
    int d = idx & 511;
    int n = (idx >> 9) & 15;
    int b = idx >> 13;
    float Aval = -expf(A_log[d * 16 + n]);
    float h = 0.f;
    for (int c = 0; c < NC; c++) {
        long si = ((long)(b * NC + c) * 16 + n) * 512 + d;
        float s = chunkS[si];
        float a = expf(Aval * sumdelta[(long)(b * NC + c) * 512 + d]);
        chunkS[si] = h;            // entry state for chunk c
        h = a * h + s;
    }
}

// yh/yl alias xmh/xml: each (r,d) reads u before writing y in the same thread.
__global__ __launch_bounds__(64) void scan_p2(const float* __restrict__ delta,
                                              const u16* xmh, const u16* xml,
                                              const float* __restrict__ dbl,
                                              const float* __restrict__ xz,
                                              const float* __restrict__ A_log,
                                              const float* __restrict__ Dv,
                                              const float* __restrict__ chunkH,
                                              u16* yh, u16* yl) {
    int b = blockIdx.x;
    int c = blockIdx.y;
    int d = blockIdx.z * 64 + threadIdx.x;
    float Arow[16];
#pragma unroll
    for (int n = 0; n < 16; n++) Arow[n] = -expf(A_log[d * 16 + n]);
    float Dd = Dv[d];
    float h[16];
    long base = ((long)(b * NC + c) * 16) * 512 + d;
#pragma unroll
    for (int n = 0; n < 16; n++) h[n] = chunkH[base + (long)n * 512];
    long r0 = (long)b * Tt + (long)c * CL;

    for (int t = 0; t < CL; t++) {
        long r = r0 + t;
        float dl  = delta[r * 512 + d];
        float u   = bf2f(xmh[r * 512 + d]) + bf2f(xml[r * 512 + d]);
        float res = xz[r * 1024 + 512 + d];
        float du  = dl * u;
        float Bn[16], Cn[16];
        const float4* Bp = (const float4*)(dbl + r * 48 + 16);
        const float4* Cp = (const float4*)(dbl + r * 48 + 32);
#pragma unroll
        for (int q = 0; q < 4; q++) {
            float4 bv = Bp[q];
            float4 cv = Cp[q];
            Bn[q*4+0] = bv.x; Bn[q*4+1] = bv.y; Bn[q*4+2] = bv.z; Bn[q*4+3] = bv.w;
            Cn[q*4+0] = cv.x; Cn[q*4+1] = cv.y; Cn[q*4+2] = cv.z; Cn[q*4+3] = cv.w;
        }
        float ysum = 0.f;
#pragma unroll
        for (int n = 0; n < 16; n++) {
            float a = expf(dl * Arow[n]);
            h[n] = a * h[n] + du * Bn[n];
            ysum += h[n] * Cn[n];
        }
        float yy = ysum + u * Dd;
        float sres = res / (1.f + expf(-res));
        float outv = yy * sres;
        u16 hh, ll;
        split2(outv, hh, ll);
        yh[r * 512 + d] = hh;
        yl[r * 512 + d] = ll;
    }
}

// ---------------------------------------------------------------------------
// Pool + head
// ---------------------------------------------------------------------------
__global__ __launch_bounds__(256) void pool_kernel(const float* __restrict__ fn,
                                                   float* __restrict__ pooled) {
    int b = blockIdx.x;
    int q = blockIdx.y;   // 16 chunks of 64 rows
    int d = threadIdx.x;
    float s = 0.f;
    for (int i = 0; i < 64; i++) {
        long t = q * 64 + i;
        s += fn[((long)b * Tt + t) * 256 + d];
    }
    atomicAdd(&pooled[b * 256 + d], s);
}

__global__ __launch_bounds__(64) void head_kernel(const float* __restrict__ pooled,
                                                  const float* __restrict__ fw,
                                                  const float* __restrict__ fb,
                                                  float* __restrict__ out) {
    int b = blockIdx.x;
    int n = threadIdx.x;
    if (n >= N_CLASSES) return;
    float s = 0.f;
    for (int k = 0; k < 256; k++) s += pooled[b * 256 + k] * fw[n * 256 + k];
    out[b * N_CLASSES + n] = s * (1.f / (float)Tt) + fb[n];
}

// ---------------------------------------------------------------------------
extern "C" void kernel_launch(void* const* d_in, const int* in_sizes, int n_in,
                              void* d_out, int out_size, void* d_ws, size_t ws_size,
                              hipStream_t stream) {
    const float* x         = (const float*)d_in[0];
    const float* embed_w   = (const float*)d_in[1];
    const float* embed_b   = (const float*)d_in[2];
    const float* pre_g     = (const float*)d_in[3];
    const float* pre_b     = (const float*)d_in[4];
    const float* in_proj_w = (const float*)d_in[5];
    const float* conv_w    = (const float*)d_in[6];
    const float* conv_b    = (const float*)d_in[7];
    const float* x_proj_w  = (const float*)d_in[8];
    const float* dt_proj_w = (const float*)d_in[9];
    const float* dt_proj_b = (const float*)d_in[10];
    const float* A_log     = (const float*)d_in[11];
    const float* Dv        = (const float*)d_in[12];
    const float* out_proj_w= (const float*)d_in[13];
    const float* post_g    = (const float*)d_in[14];
    const float* post_b    = (const float*)d_in[15];
    const float* fine_w    = (const float*)d_in[16];
    const float* fine_b    = (const float*)d_in[17];
    float* out = (float*)d_out;
    char* base = (char*)d_ws;

    // workspace layout (bytes) — total 87,924,736 (< 91.7 MB proven cap)
    float* feat    = (float*)(base + 0);          //  8 MB fp32 [M,256]
    float* xz      = (float*)(base + 8388608);    // 32 MB fp32 [M,1024]
    float* delta   = (float*)(base + 41943040);   // 16 MB fp32 [M,512]; later post-LN out
    u16*   xmh     = (u16*)  (base + 58720256);   //  8 MB bf16 [M,512]  (-> y hi)
    u16*   xml     = (u16*)  (base + 67108864);   //  8 MB bf16 [M,512]  (-> y lo)
    u16*   fbh     = (u16*)  (base + 75497472);   //  4 MB featbf hi -> hn hi
    u16*   fbl     = (u16*)  (base + 79691776);   //  4 MB featbf lo -> hn lo
    float* chunkS  = (float*)(base + 75497472);   //  8 MB overlays fbh/fbl (dead by then)
    float* dbl     = (float*)(base + 83886080);   //  1.5 MB fp32 [M,48]
    float* sumdelta= (float*)(base + 85458944);   //  0.5 MB
    float* pooled  = (float*)(base + 85983232);   //  8 KB
    u16*   ebh     = (u16*)  (base + 85991424);   // weight bf16 buffers
    u16*   ebl     = ebh + 65536;
    u16*   iph     = ebl + 65536;
    u16*   ipl     = iph + 262144;
    u16*   xph     = ipl + 262144;
    u16*   xpl     = xph + 24576;
    u16*   oph     = xpl + 24576;
    u16*   opl     = oph + 131072;
    float* lnout   = delta;                        // post-LN fp32 reuses delta

    // 1. featurize -> bf16 hi/lo (Kpad 256)
    feat_kernel<<<dim3(Mrows), dim3(256), 0, stream>>>(x, fbh, fbl);

    // 2. all weight conversions in one dispatch (483328 elems)
    wcvt_kernel<<<dim3(1888), dim3(256), 0, stream>>>(
        embed_w, in_proj_w, x_proj_w, out_proj_w,
        ebh, ebl, iph, ipl, xph, xpl, oph, opl);

    // 3. embed: feat = featbf @ ebw^T + bias   (M=8192,N=256,K=256p)
    gemm_mfma<128,64,1><<<dim3(4, 64), dim3(256), 0, stream>>>(
        fbh, fbl, 256, ebh, ebl, 256, embed_b, nullptr, 0, feat, 256, Mrows, 256, 256);

    // 4. pre-LN -> hn bf16 hi/lo (overwrites featbf region; embed done)
    ln_kernel<<<dim3(Mrows), dim3(256), 0, stream>>>(feat, pre_g, pre_b,
                                                     nullptr, fbh, fbl, 1);

    // 5. in_proj: xz = hn @ ipw^T  (M=8192,N=1024,K=256)
    gemm_mfma<128,128,0><<<dim3(8, 64), dim3(256), 0, stream>>>(
        fbh, fbl, 256, iph, ipl, 256, nullptr, nullptr, 0, xz, 1024, Mrows, 1024, 256);

    // 6. conv + silu -> xm bf16 hi/lo
    conv_silu_kernel<<<dim3(Mrows, 2), dim3(256), 0, stream>>>(xz, conv_w, conv_b, xmh, xml);

    // 7. x_proj: dbl = xm @ xpw^T  (M=8192,N=48,K=512)
    gemm_mfma<64,64,0><<<dim3(1, 128), dim3(256), 0, stream>>>(
        xmh, xml, 512, xph, xpl, 512, nullptr, nullptr, 0, dbl, 48, Mrows, 48, 512);

    // 8. dt_proj + softplus -> delta
    dtproj_kernel<<<dim3(Mrows / 4), dim3(256), 0, stream>>>(dbl, dt_proj_w, dt_proj_b, delta);

    // 9. chunked selective scan; p2 writes y bf16 in-place over xm bf16
    scan_p1<<<dim3(Bb, NC, 8), dim3(64), 0, stream>>>(delta, xmh, xml, dbl, A_log, chunkS, sumdelta);
    scan_combine<<<dim3(256), dim3(256), 0, stream>>>(chunkS, sumdelta, A_log);
    scan_p2<<<dim3(Bb, NC, 8), dim3(64), 0, stream>>>(delta, xmh, xml, dbl, xz, A_log, Dv,
                                                      chunkS, xmh, xml);

    // 10. out_proj + residual: feat += y @ opw^T  (M=8192,N=256,K=512)
    gemm_mfma<128,64,3><<<dim3(4, 64), dim3(256), 0, stream>>>(
        xmh, xml, 512, oph, opl, 512, nullptr, feat, 256, feat, 256, Mrows, 256, 512);

    // 11. post-LN -> fp32 (into delta region, dead after scan)
    ln_kernel<<<dim3(Mrows), dim3(256), 0, stream>>>(feat, post_g, post_b,
                                                     lnout, nullptr, nullptr, 0);

    // 12. pool + head
    hipMemsetAsync(pooled, 0, Bb * 256 * sizeof(float), stream);
    pool_kernel<<<dim3(Bb, 16), dim3(256), 0, stream>>>(lnout, pooled);
    head_kernel<<<dim3(Bb), dim3(64), 0, stream>>>(pooled, fine_w, fine_b, out);
}

// Round 5
// 298.267 us; speedup vs baseline: 4.8025x; 1.1988x over previous
//
#include <hip/hip_runtime.h>
#include <hip/hip_bf16.h>
#include <math.h>

// Problem constants
#define Bb 8
#define Tt 1024
#define Jj 25
#define D_MODEL 256
#define D_STATE 16
#define D_CONV 4
#define D_INNER 512
#define DT_RANK 16
#define N_CLASSES 60
#define Mrows (Bb*Tt)   // 8192
#define NC 64           // scan chunks
#define CL 16           // chunk length (NC*CL == Tt)

typedef unsigned short u16;
using bf16x8 = __attribute__((ext_vector_type(8))) __bf16;
using f32x4  = __attribute__((ext_vector_type(4))) float;

// ---- bf16 split helpers ----------------------------------------------------
__device__ inline u16 f2bf(float x) {
    unsigned u = __float_as_uint(x);
    unsigned r = (u + 0x7fffu + ((u >> 16) & 1u)) >> 16;
    return (u16)r;
}
__device__ inline float bf2f(u16 h) { return __uint_as_float((unsigned)h << 16); }
__device__ inline void split2(float x, u16& h, u16& l) {
    h = f2bf(x);
    l = f2bf(x - bf2f(h));
}
// fast softplus: max(s,0) + log(1+exp(-|s|)) with native exp/log
__device__ inline float softplus_fast(float s) {
    return fmaxf(s, 0.f) + __logf(1.f + __expf(-fabsf(s)));
}

__device__ inline f32x4 mfma3(bf16x8 ah, bf16x8 al, bf16x8 bh, bf16x8 bl, f32x4 c) {
    c = __builtin_amdgcn_mfma_f32_16x16x32_bf16(al, bh, c, 0, 0, 0);
    c = __builtin_amdgcn_mfma_f32_16x16x32_bf16(ah, bl, c, 0, 0, 0);
    c = __builtin_amdgcn_mfma_f32_16x16x32_bf16(ah, bh, c, 0, 0, 0);
    return c;
}

// ---------------------------------------------------------------------------
// featurize -> featbf hi/lo (M, 256) bf16, zero-padded K 225->256
// ---------------------------------------------------------------------------
__global__ __launch_bounds__(256) void feat_kernel(const float* __restrict__ x,
                                                   u16* __restrict__ fh,
                                                   u16* __restrict__ fl) {
    int r = blockIdx.x;          // 0..8191
    int c = threadIdx.x;         // 0..255
    float v = 0.f;
    if (c < 225) {
        int t = r & (Tt - 1);
        int j = c / 9;
        int cc = c - j * 9;
        int comp = cc % 3;
        int kind = cc / 3;
        auto POS = [&](int dt) -> float {
            const float* p = x + (long)(r - dt) * Jj * 3;
            return p[j * 3 + comp] - p[comp];
        };
        if (kind == 0) {
            v = POS(0);
        } else if (kind == 1) {
            v = (t >= 1) ? (POS(0) - POS(1)) : 0.f;
        } else {
            if (t >= 2)      v = POS(0) - 2.f * POS(1) + POS(2);
            else if (t == 1) v = POS(0) - POS(1);
            else             v = 0.f;
        }
    }
    u16 h, l;
    split2(v, h, l);
    fh[(long)r * 256 + c] = h;
    fl[(long)r * 256 + c] = l;
}

// ---------------------------------------------------------------------------
// Weight fp32 -> bf16 hi/lo (k-padded). One dispatch for all 4 weights.
// ---------------------------------------------------------------------------
__global__ __launch_bounds__(256) void wcvt_kernel(
    const float* __restrict__ ew, const float* __restrict__ iw,
    const float* __restrict__ xw, const float* __restrict__ ow,
    u16* __restrict__ ebh, u16* __restrict__ ebl,
    u16* __restrict__ iph, u16* __restrict__ ipl,
    u16* __restrict__ xph, u16* __restrict__ xpl,
    u16* __restrict__ oph, u16* __restrict__ opl) {
    int i = blockIdx.x * 256 + threadIdx.x;   // 0..483327
    const float* src; u16 *dh, *dl; int K, kshift, idx;
    if (i < 65536)       { src = ew; dh = ebh; dl = ebl; K = 225; kshift = 8; idx = i; }
    else if (i < 327680) { src = iw; dh = iph; dl = ipl; K = 256; kshift = 8; idx = i - 65536; }
    else if (i < 352256) { src = xw; dh = xph; dl = xpl; K = 512; kshift = 9; idx = i - 327680; }
    else                 { src = ow; dh = oph; dl = opl; K = 512; kshift = 9; idx = i - 352256; }
    int n = idx >> kshift;
    int k = idx & ((1 << kshift) - 1);
    float v = (k < K) ? src[(long)n * K + k] : 0.f;
    u16 h, l;
    split2(v, h, l);
    dh[idx] = h;
    dl[idx] = l;
}

// ---------------------------------------------------------------------------
// bf16x3 MFMA GEMM (unchanged from R4)
// ---------------------------------------------------------------------------
template<int BM, int BN, int EPI>
__global__ __launch_bounds__(256) void gemm_mfma(
    const u16* __restrict__ Ahi, const u16* __restrict__ Alo, int lda,
    const u16* __restrict__ Whi, const u16* __restrict__ Wlo, int ldw,
    const float* __restrict__ bias, const float* __restrict__ resid, int ldr,
    float* __restrict__ C, int ldc, int M, int N, int K)
{
    constexpr int TM = BM / 32;
    constexpr int TN = BN / 32;
    constexpr int SA = 40;
    __shared__ u16 AsH[BM * SA], AsL[BM * SA];
    __shared__ u16 WsH[BN * SA], WsL[BN * SA];
    int tid = threadIdx.x;
    int m0 = blockIdx.y * BM;
    int n0 = blockIdx.x * BN;
    int lane = tid & 63;
    int wave = tid >> 6;
    int wm = wave >> 1, wn = wave & 1;
    int fr = lane & 15, quad = lane >> 4;
    f32x4 acc[TM][TN] = {};

    for (int k0 = 0; k0 < K; k0 += 32) {
        for (int s = tid; s < BM * 4; s += 256) {
            int row = s >> 2, seg = s & 3;
            long off = (long)(m0 + row) * lda + k0 + seg * 8;
            *(uint4*)&AsH[row * SA + seg * 8] = *(const uint4*)(Ahi + off);
            *(uint4*)&AsL[row * SA + seg * 8] = *(const uint4*)(Alo + off);
        }
        for (int s = tid; s < BN * 4; s += 256) {
            int row = s >> 2, seg = s & 3;
            uint4 vh = make_uint4(0, 0, 0, 0), vl = make_uint4(0, 0, 0, 0);
            if (n0 + row < N) {
                long off = (long)(n0 + row) * ldw + k0 + seg * 8;
                vh = *(const uint4*)(Whi + off);
                vl = *(const uint4*)(Wlo + off);
            }
            *(uint4*)&WsH[row * SA + seg * 8] = vh;
            *(uint4*)&WsL[row * SA + seg * 8] = vl;
        }
        __syncthreads();
        bf16x8 aH[TM], aL[TM], bH[TN], bL[TN];
#pragma unroll
        for (int im = 0; im < TM; im++) {
            int r = wm * (BM / 2) + im * 16 + fr;
            aH[im] = *(const bf16x8*)&AsH[r * SA + quad * 8];
            aL[im] = *(const bf16x8*)&AsL[r * SA + quad * 8];
        }
#pragma unroll
        for (int in = 0; in < TN; in++) {
            int r = wn * (BN / 2) + in * 16 + fr;
            bH[in] = *(const bf16x8*)&WsH[r * SA + quad * 8];
            bL[in] = *(const bf16x8*)&WsL[r * SA + quad * 8];
        }
#pragma unroll
        for (int im = 0; im < TM; im++)
#pragma unroll
            for (int in = 0; in < TN; in++)
                acc[im][in] = mfma3(aH[im], aL[im], bH[in], bL[in], acc[im][in]);
        __syncthreads();
    }
#pragma unroll
    for (int im = 0; im < TM; im++) {
#pragma unroll
        for (int in = 0; in < TN; in++) {
#pragma unroll
            for (int reg = 0; reg < 4; reg++) {
                int gm = m0 + wm * (BM / 2) + im * 16 + quad * 4 + reg;
                int gn = n0 + wn * (BN / 2) + in * 16 + fr;
                if (gn >= N) continue;
                float v = acc[im][in][reg];
                if (EPI == 1) v += bias[gn];
                if (EPI == 3) v += resid[(long)gm * ldr + gn];
                C[(long)gm * ldc + gn] = v;
            }
        }
    }
}

// ---------------------------------------------------------------------------
// LayerNorm over D=256 per row. bf=1: write bf16 hi/lo; bf=0: write fp32.
// ---------------------------------------------------------------------------
__global__ __launch_bounds__(256) void ln_kernel(const float* __restrict__ x,
                                                 const float* __restrict__ g,
                                                 const float* __restrict__ b,
                                                 float* outf, u16* outh, u16* outl,
                                                 int bf) {
    __shared__ float red[256];
    long r = blockIdx.x;
    int d = threadIdx.x;
    float v = x[r * 256 + d];
    red[d] = v;
    __syncthreads();
    for (int s = 128; s > 0; s >>= 1) {
        if (d < s) red[d] += red[d + s];
        __syncthreads();
    }
    float mu = red[0] * (1.f / 256.f);
    __syncthreads();
    float dv = v - mu;
    red[d] = dv * dv;
    __syncthreads();
    for (int s = 128; s > 0; s >>= 1) {
        if (d < s) red[d] += red[d + s];
        __syncthreads();
    }
    float var = red[0] * (1.f / 256.f);
    float o = dv * rsqrtf(var + 1e-5f) * g[d] + b[d];
    if (bf) {
        u16 h, l;
        split2(o, h, l);
        outh[r * 256 + d] = h;
        outl[r * 256 + d] = l;
    } else {
        outf[r * 256 + d] = o;
    }
}

// ---------------------------------------------------------------------------
// Causal depthwise conv (k=4) + SiLU -> xm bf16 hi/lo
// ---------------------------------------------------------------------------
__global__ __launch_bounds__(256) void conv_silu_kernel(const float* __restrict__ xz,
                                                        const float* __restrict__ cw,
                                                        const float* __restrict__ cb,
                                                        u16* __restrict__ xmh,
                                                        u16* __restrict__ xml) {
    int r = blockIdx.x;                      // 0..8191
    int d = blockIdx.y * 256 + threadIdx.x;  // 0..511
    int t = r & (Tt - 1);
    float w0 = cw[d * 4 + 0], w1 = cw[d * 4 + 1], w2 = cw[d * 4 + 2], w3 = cw[d * 4 + 3];
    float acc = cb[d];
    acc += w3 * xz[(long)r * 1024 + d];
    if (t >= 1) acc += w2 * xz[(long)(r - 1) * 1024 + d];
    if (t >= 2) acc += w1 * xz[(long)(r - 2) * 1024 + d];
    if (t >= 3) acc += w0 * xz[(long)(r - 3) * 1024 + d];
    float s = acc / (1.f + __expf(-acc));
    u16 h, l;
    split2(s, h, l);
    xmh[(long)r * 512 + d] = h;
    xml[(long)r * 512 + d] = l;
}

// ---------------------------------------------------------------------------
// Chunked selective scan, dt_proj fused (delta computed inline from dbl[:,0:16]).
// NC=64 chunks of CL=16. All exps native.
// ---------------------------------------------------------------------------
__device__ inline float delta_inline(const float* __restrict__ dblrow,
                                     const float4 wd[4], float bias) {
    float4 t0 = *(const float4*)(dblrow + 0);
    float4 t1 = *(const float4*)(dblrow + 4);
    float4 t2 = *(const float4*)(dblrow + 8);
    float4 t3 = *(const float4*)(dblrow + 12);
    float s = bias;
    s += t0.x * wd[0].x + t0.y * wd[0].y + t0.z * wd[0].z + t0.w * wd[0].w;
    s += t1.x * wd[1].x + t1.y * wd[1].y + t1.z * wd[1].z + t1.w * wd[1].w;
    s += t2.x * wd[2].x + t2.y * wd[2].y + t2.z * wd[2].z + t2.w * wd[2].w;
    s += t3.x * wd[3].x + t3.y * wd[3].y + t3.z * wd[3].z + t3.w * wd[3].w;
    return softplus_fast(s);
}

__global__ __launch_bounds__(64) void scan_p1(const float* __restrict__ dbl,
                                              const float* __restrict__ dtw,
                                              const float* __restrict__ dtb,
                                              const u16* __restrict__ xmh,
                                              const u16* __restrict__ xml,
                                              const float* __restrict__ A_log,
                                              float* __restrict__ chunkS,
                                              float* __restrict__ sumdelta) {
    int b = blockIdx.x;                      // 0..7
    int c = blockIdx.y;                      // 0..NC-1
    int d = blockIdx.z * 64 + threadIdx.x;   // 0..511
    float Arow[16];
#pragma unroll
    for (int n = 0; n < 16; n++) Arow[n] = -expf(A_log[d * 16 + n]);
    float4 wd[4];
#pragma unroll
    for (int q = 0; q < 4; q++) wd[q] = *(const float4*)(dtw + d * 16 + q * 4);
    float bdt = dtb[d];
    float S[16];
#pragma unroll
    for (int n = 0; n < 16; n++) S[n] = 0.f;
    float sd = 0.f;
    long r0 = (long)b * Tt + (long)c * CL;

    for (int t = 0; t < CL; t++) {
        long r = r0 + t;
        float dl = delta_inline(dbl + r * 48, wd, bdt);
        float u  = bf2f(xmh[r * 512 + d]) + bf2f(xml[r * 512 + d]);
        float du = dl * u;
        sd += dl;
        float Bn[16];
        const float4* Bp = (const float4*)(dbl + r * 48 + 16);
#pragma unroll
        for (int q = 0; q < 4; q++) {
            float4 bv = Bp[q];
            Bn[q*4+0] = bv.x; Bn[q*4+1] = bv.y; Bn[q*4+2] = bv.z; Bn[q*4+3] = bv.w;
        }
#pragma unroll
        for (int n = 0; n < 16; n++) {
            float a = __expf(dl * Arow[n]);
            S[n] = a * S[n] + du * Bn[n];
        }
    }
    long base = ((long)(b * NC + c) * 16) * 512 + d;
#pragma unroll
    for (int n = 0; n < 16; n++) chunkS[base + (long)n * 512] = S[n];
    sumdelta[(long)(b * NC + c) * 512 + d] = sd;
}

__global__ __launch_bounds__(256) void scan_combine(float* chunkS,
                                                    const float* __restrict__ sumdelta,
                                                    const float* __restrict__ A_log) {
    int idx = blockIdx.x * 256 + threadIdx.x;   // 0..65535
    int d = idx & 511;
    int n = (idx >> 9) & 15;
    int b = idx >> 13;
    float Aval = -expf(A_log[d * 16 + n]);
    float h = 0.f;
    for (int c = 0; c < NC; c++) {
        long si = ((long)(b * NC + c) * 16 + n) * 512 + d;
        float s = chunkS[si];
        float a = __expf(Aval * sumdelta[(long)(b * NC + c) * 512 + d]);
        chunkS[si] = h;            // entry state for chunk c
        h = a * h + s;
    }
}

// yh/yl alias xmh/xml: each (r,d) reads u before writing y in the same thread.
__global__ __launch_bounds__(64) void scan_p2(const float* __restrict__ dbl,
                                              const float* __restrict__ dtw,
                                              const float* __restrict__ dtb,
                                              const u16* xmh, const u16* xml,
                                              const float* __restrict__ xz,
                                              const float* __restrict__ A_log,
                                              const float* __restrict__ Dv,
                                              const float* __restrict__ chunkH,
                                              u16* yh, u16* yl) {
    int b = blockIdx.x;
    int c = blockIdx.y;
    int d = blockIdx.z * 64 + threadIdx.x;
    float Arow[16];
#pragma unroll
    for (int n = 0; n < 16; n++) Arow[n] = -expf(A_log[d * 16 + n]);
    float4 wd[4];
#pragma unroll
    for (int q = 0; q < 4; q++) wd[q] = *(const float4*)(dtw + d * 16 + q * 4);
    float bdt = dtb[d];
    float Dd = Dv[d];
    float h[16];
    long base = ((long)(b * NC + c) * 16) * 512 + d;
#pragma unroll
    for (int n = 0; n < 16; n++) h[n] = chunkH[base + (long)n * 512];
    long r0 = (long)b * Tt + (long)c * CL;

    for (int t = 0; t < CL; t++) {
        long r = r0 + t;
        float dl  = delta_inline(dbl + r * 48, wd, bdt);
        float u   = bf2f(xmh[r * 512 + d]) + bf2f(xml[r * 512 + d]);
        float res = xz[r * 1024 + 512 + d];
        float du  = dl * u;
        float Bn[16], Cn[16];
        const float4* Bp = (const float4*)(dbl + r * 48 + 16);
        const float4* Cp = (const float4*)(dbl + r * 48 + 32);
#pragma unroll
        for (int q = 0; q < 4; q++) {
            float4 bv = Bp[q];
            float4 cv = Cp[q];
            Bn[q*4+0] = bv.x; Bn[q*4+1] = bv.y; Bn[q*4+2] = bv.z; Bn[q*4+3] = bv.w;
            Cn[q*4+0] = cv.x; Cn[q*4+1] = cv.y; Cn[q*4+2] = cv.z; Cn[q*4+3] = cv.w;
        }
        float ysum = 0.f;
#pragma unroll
        for (int n = 0; n < 16; n++) {
            float a = __expf(dl * Arow[n]);
            h[n] = a * h[n] + du * Bn[n];
            ysum += h[n] * Cn[n];
        }
        float yy = ysum + u * Dd;
        float sres = res / (1.f + __expf(-res));
        float outv = yy * sres;
        u16 hh, ll;
        split2(outv, hh, ll);
        yh[r * 512 + d] = hh;
        yl[r * 512 + d] = ll;
    }
}

// ---------------------------------------------------------------------------
// Pool + head
// ---------------------------------------------------------------------------
__global__ __launch_bounds__(256) void pool_kernel(const float* __restrict__ fn,
                                                   float* __restrict__ pooled) {
    int b = blockIdx.x;
    int q = blockIdx.y;   // 16 chunks of 64 rows
    int d = threadIdx.x;
    float s = 0.f;
    for (int i = 0; i < 64; i++) {
        long t = q * 64 + i;
        s += fn[((long)b * Tt + t) * 256 + d];
    }
    atomicAdd(&pooled[b * 256 + d], s);
}

__global__ __launch_bounds__(64) void head_kernel(const float* __restrict__ pooled,
                                                  const float* __restrict__ fw,
                                                  const float* __restrict__ fb,
                                                  float* __restrict__ out) {
    int b = blockIdx.x;
    int n = threadIdx.x;
    if (n >= N_CLASSES) return;
    float s = 0.f;
    for (int k = 0; k < 256; k++) s += pooled[b * 256 + k] * fw[n * 256 + k];
    out[b * N_CLASSES + n] = s * (1.f / (float)Tt) + fb[n];
}

// ---------------------------------------------------------------------------
extern "C" void kernel_launch(void* const* d_in, const int* in_sizes, int n_in,
                              void* d_out, int out_size, void* d_ws, size_t ws_size,
                              hipStream_t stream) {
    const float* x         = (const float*)d_in[0];
    const float* embed_w   = (const float*)d_in[1];
    const float* embed_b   = (const float*)d_in[2];
    const float* pre_g     = (const float*)d_in[3];
    const float* pre_b     = (const float*)d_in[4];
    const float* in_proj_w = (const float*)d_in[5];
    const float* conv_w    = (const float*)d_in[6];
    const float* conv_b    = (const float*)d_in[7];
    const float* x_proj_w  = (const float*)d_in[8];
    const float* dt_proj_w = (const float*)d_in[9];
    const float* dt_proj_b = (const float*)d_in[10];
    const float* A_log     = (const float*)d_in[11];
    const float* Dv        = (const float*)d_in[12];
    const float* out_proj_w= (const float*)d_in[13];
    const float* post_g    = (const float*)d_in[14];
    const float* post_b    = (const float*)d_in[15];
    const float* fine_w    = (const float*)d_in[16];
    const float* fine_b    = (const float*)d_in[17];
    float* out = (float*)d_out;
    char* base = (char*)d_ws;

    // workspace layout (bytes) — total ~88.4 MB (< 91.8 MB proven cap)
    float* feat    = (float*)(base + 0);          //  8 MB fp32 [M,256]
    float* xz      = (float*)(base + 8388608);    // 32 MB fp32 [M,1024]
    float* chunkS  = (float*)(base + 41943040);   // 16 MB [8*NC,16,512]; later post-LN out
    u16*   xmh     = (u16*)  (base + 58720256);   //  8 MB bf16 [M,512]  (-> y hi)
    u16*   xml     = (u16*)  (base + 67108864);   //  8 MB bf16 [M,512]  (-> y lo)
    u16*   fbh     = (u16*)  (base + 75497472);   //  4 MB featbf hi -> hn hi
    u16*   fbl     = (u16*)  (base + 79691776);   //  4 MB featbf lo -> hn lo
    float* dbl     = (float*)(base + 83886080);   //  1.5 MB fp32 [M,48]
    float* sumdelta= (float*)(base + 85458944);   //  1 MB [8*NC,512]
    float* pooled  = (float*)(base + 86507520);   //  8 KB
    u16*   ebh     = (u16*)  (base + 86515712);   // weight bf16 buffers (~1.9 MB)
    u16*   ebl     = ebh + 65536;
    u16*   iph     = ebl + 65536;
    u16*   ipl     = iph + 262144;
    u16*   xph     = ipl + 262144;
    u16*   xpl     = xph + 24576;
    u16*   oph     = xpl + 24576;
    u16*   opl     = oph + 131072;
    float* lnout   = chunkS;                      // post-LN fp32 reuses chunkS (dead)

    // 1. featurize -> bf16 hi/lo (Kpad 256)
    feat_kernel<<<dim3(Mrows), dim3(256), 0, stream>>>(x, fbh, fbl);

    // 2. all weight conversions in one dispatch
    wcvt_kernel<<<dim3(1888), dim3(256), 0, stream>>>(
        embed_w, in_proj_w, x_proj_w, out_proj_w,
        ebh, ebl, iph, ipl, xph, xpl, oph, opl);

    // 3. embed: feat = featbf @ ebw^T + bias   (M=8192,N=256,K=256p)
    gemm_mfma<128,64,1><<<dim3(4, 64), dim3(256), 0, stream>>>(
        fbh, fbl, 256, ebh, ebl, 256, embed_b, nullptr, 0, feat, 256, Mrows, 256, 256);

    // 4. pre-LN -> hn bf16 hi/lo
    ln_kernel<<<dim3(Mrows), dim3(256), 0, stream>>>(feat, pre_g, pre_b,
                                                     nullptr, fbh, fbl, 1);

    // 5. in_proj: xz = hn @ ipw^T  (M=8192,N=1024,K=256)
    gemm_mfma<128,128,0><<<dim3(8, 64), dim3(256), 0, stream>>>(
        fbh, fbl, 256, iph, ipl, 256, nullptr, nullptr, 0, xz, 1024, Mrows, 1024, 256);

    // 6. conv + silu -> xm bf16 hi/lo
    conv_silu_kernel<<<dim3(Mrows, 2), dim3(256), 0, stream>>>(xz, conv_w, conv_b, xmh, xml);

    // 7. x_proj: dbl = xm @ xpw^T  (M=8192,N=48,K=512)
    gemm_mfma<64,64,0><<<dim3(1, 128), dim3(256), 0, stream>>>(
        xmh, xml, 512, xph, xpl, 512, nullptr, nullptr, 0, dbl, 48, Mrows, 48, 512);

    // 8. chunked selective scan, dt_proj fused; p2 writes y bf16 over xm
    scan_p1<<<dim3(Bb, NC, 8), dim3(64), 0, stream>>>(
        dbl, dt_proj_w, dt_proj_b, xmh, xml, A_log, chunkS, sumdelta);
    scan_combine<<<dim3(256), dim3(256), 0, stream>>>(chunkS, sumdelta, A_log);
    scan_p2<<<dim3(Bb, NC, 8), dim3(64), 0, stream>>>(
        dbl, dt_proj_w, dt_proj_b, xmh, xml, xz, A_log, Dv, chunkS, xmh, xml);

    // 9. out_proj + residual: feat += y @ opw^T  (M=8192,N=256,K=512)
    gemm_mfma<128,64,3><<<dim3(4, 64), dim3(256), 0, stream>>>(
        xmh, xml, 512, oph, opl, 512, nullptr, feat, 256, feat, 256, Mrows, 256, 512);

    // 10. post-LN -> fp32 (into chunkS region, dead after scan)
    ln_kernel<<<dim3(Mrows), dim3(256), 0, stream>>>(feat, post_g, post_b,
                                                     lnout, nullptr, nullptr, 0);

    // 11. pool + head
    hipMemsetAsync(pooled, 0, Bb * 256 * sizeof(float), stream);
    pool_kernel<<<dim3(Bb, 16), dim3(256), 0, stream>>>(lnout, pooled);
    head_kernel<<<dim3(Bb), dim3(64), 0, stream>>>(pooled, fine_w, fine_b, out);
}

// Round 6
// 272.132 us; speedup vs baseline: 5.2638x; 1.0960x over previous
//
#include <hip/hip_runtime.h>
#include <hip/hip_bf16.h>
#include <math.h>

// Problem constants
#define Bb 8
#define Tt 1024
#define Jj 25
#define D_MODEL 256
#define D_STATE 16
#define D_CONV 4
#define D_INNER 512
#define DT_RANK 16
#define N_CLASSES 60
#define Mrows (Bb*Tt)   // 8192
#define NC 64           // scan chunks
#define CL 16           // chunk length (NC*CL == Tt)

typedef unsigned short u16;
using bf16x8 = __attribute__((ext_vector_type(8))) __bf16;
using f32x4  = __attribute__((ext_vector_type(4))) float;

// ---- bf16 split helpers ----------------------------------------------------
__device__ inline u16 f2bf(float x) {
    unsigned u = __float_as_uint(x);
    unsigned r = (u + 0x7fffu + ((u >> 16) & 1u)) >> 16;
    return (u16)r;
}
__device__ inline float bf2f(u16 h) { return __uint_as_float((unsigned)h << 16); }
__device__ inline void split2(float x, u16& h, u16& l) {
    h = f2bf(x);
    l = f2bf(x - bf2f(h));
}
__device__ inline float softplus_fast(float s) {
    return fmaxf(s, 0.f) + __logf(1.f + __expf(-fabsf(s)));
}
__device__ inline f32x4 mfma3(bf16x8 ah, bf16x8 al, bf16x8 bh, bf16x8 bl, f32x4 c) {
    c = __builtin_amdgcn_mfma_f32_16x16x32_bf16(al, bh, c, 0, 0, 0);
    c = __builtin_amdgcn_mfma_f32_16x16x32_bf16(ah, bl, c, 0, 0, 0);
    c = __builtin_amdgcn_mfma_f32_16x16x32_bf16(ah, bh, c, 0, 0, 0);
    return c;
}

// ---------------------------------------------------------------------------
// prep: blocks 0..8191 featurize -> fh/fl; blocks 8192.. weight cvt
// ---------------------------------------------------------------------------
__global__ __launch_bounds__(256) void prep_kernel(
    const float* __restrict__ x, u16* __restrict__ fh, u16* __restrict__ fl,
    const float* __restrict__ ew, const float* __restrict__ iw,
    const float* __restrict__ xw, const float* __restrict__ ow,
    u16* __restrict__ ebh, u16* __restrict__ ebl,
    u16* __restrict__ iph, u16* __restrict__ ipl,
    u16* __restrict__ xph, u16* __restrict__ xpl,
    u16* __restrict__ oph, u16* __restrict__ opl) {
    int blk = blockIdx.x;
    if (blk < Mrows) {
        int r = blk;
        int c = threadIdx.x;
        float v = 0.f;
        if (c < 225) {
            int t = r & (Tt - 1);
            int j = c / 9;
            int cc = c - j * 9;
            int comp = cc % 3;
            int kind = cc / 3;
            auto POS = [&](int dt) -> float {
                const float* p = x + (long)(r - dt) * Jj * 3;
                return p[j * 3 + comp] - p[comp];
            };
            if (kind == 0) v = POS(0);
            else if (kind == 1) v = (t >= 1) ? (POS(0) - POS(1)) : 0.f;
            else {
                if (t >= 2)      v = POS(0) - 2.f * POS(1) + POS(2);
                else if (t == 1) v = POS(0) - POS(1);
                else             v = 0.f;
            }
        }
        u16 h, l;
        split2(v, h, l);
        fh[(long)r * 256 + c] = h;
        fl[(long)r * 256 + c] = l;
    } else {
        int i = (blk - Mrows) * 256 + threadIdx.x;   // 0..483327
        const float* src; u16 *dh, *dl; int K, kshift, idx;
        if (i < 65536)       { src = ew; dh = ebh; dl = ebl; K = 225; kshift = 8; idx = i; }
        else if (i < 327680) { src = iw; dh = iph; dl = ipl; K = 256; kshift = 8; idx = i - 65536; }
        else if (i < 352256) { src = xw; dh = xph; dl = xpl; K = 512; kshift = 9; idx = i - 327680; }
        else                 { src = ow; dh = oph; dl = opl; K = 512; kshift = 9; idx = i - 352256; }
        int n = idx >> kshift;
        int k = idx & ((1 << kshift) - 1);
        float v = (k < K) ? src[(long)n * K + k] : 0.f;
        u16 h, l;
        split2(v, h, l);
        dh[idx] = h;
        dl[idx] = l;
    }
}

// ---------------------------------------------------------------------------
// generic bf16x3 MFMA GEMM (used for in_proj, x_proj)
// ---------------------------------------------------------------------------
template<int BM, int BN>
__global__ __launch_bounds__(256) void gemm_mfma(
    const u16* __restrict__ Ahi, const u16* __restrict__ Alo, int lda,
    const u16* __restrict__ Whi, const u16* __restrict__ Wlo, int ldw,
    float* __restrict__ C, int ldc, int M, int N, int K)
{
    constexpr int TM = BM / 32;
    constexpr int TN = BN / 32;
    constexpr int SA = 40;
    __shared__ u16 AsH[BM * SA], AsL[BM * SA];
    __shared__ u16 WsH[BN * SA], WsL[BN * SA];
    int tid = threadIdx.x;
    int m0 = blockIdx.y * BM;
    int n0 = blockIdx.x * BN;
    int lane = tid & 63;
    int wave = tid >> 6;
    int wm = wave >> 1, wn = wave & 1;
    int fr = lane & 15, quad = lane >> 4;
    f32x4 acc[TM][TN] = {};

    for (int k0 = 0; k0 < K; k0 += 32) {
        for (int s = tid; s < BM * 4; s += 256) {
            int row = s >> 2, seg = s & 3;
            long off = (long)(m0 + row) * lda + k0 + seg * 8;
            *(uint4*)&AsH[row * SA + seg * 8] = *(const uint4*)(Ahi + off);
            *(uint4*)&AsL[row * SA + seg * 8] = *(const uint4*)(Alo + off);
        }
        for (int s = tid; s < BN * 4; s += 256) {
            int row = s >> 2, seg = s & 3;
            uint4 vh = make_uint4(0, 0, 0, 0), vl = make_uint4(0, 0, 0, 0);
            if (n0 + row < N) {
                long off = (long)(n0 + row) * ldw + k0 + seg * 8;
                vh = *(const uint4*)(Whi + off);
                vl = *(const uint4*)(Wlo + off);
            }
            *(uint4*)&WsH[row * SA + seg * 8] = vh;
            *(uint4*)&WsL[row * SA + seg * 8] = vl;
        }
        __syncthreads();
        bf16x8 aH[TM], aL[TM], bH[TN], bL[TN];
#pragma unroll
        for (int im = 0; im < TM; im++) {
            int r = wm * (BM / 2) + im * 16 + fr;
            aH[im] = *(const bf16x8*)&AsH[r * SA + quad * 8];
            aL[im] = *(const bf16x8*)&AsL[r * SA + quad * 8];
        }
#pragma unroll
        for (int in = 0; in < TN; in++) {
            int r = wn * (BN / 2) + in * 16 + fr;
            bH[in] = *(const bf16x8*)&WsH[r * SA + quad * 8];
            bL[in] = *(const bf16x8*)&WsL[r * SA + quad * 8];
        }
#pragma unroll
        for (int im = 0; im < TM; im++)
#pragma unroll
            for (int in = 0; in < TN; in++)
                acc[im][in] = mfma3(aH[im], aL[im], bH[in], bL[in], acc[im][in]);
        __syncthreads();
    }
#pragma unroll
    for (int im = 0; im < TM; im++) {
#pragma unroll
        for (int in = 0; in < TN; in++) {
#pragma unroll
            for (int reg = 0; reg < 4; reg++) {
                int gm = m0 + wm * (BM / 2) + im * 16 + quad * 4 + reg;
                int gn = n0 + wn * (BN / 2) + in * 16 + fr;
                if (gn >= N) continue;
                C[(long)gm * ldc + gn] = acc[im][in][reg];
            }
        }
    }
}

// ---------------------------------------------------------------------------
// embed GEMM + bias + pre-LN fused. BM=64, BN=256 (full row), K=256.
// A = featbf hi/lo [M,256]; W = ebw hi/lo [256,256].
// Writes feat fp32 and hn bf16 hi/lo (hn aliases A rows — safe, block-local).
// ---------------------------------------------------------------------------
__global__ __launch_bounds__(256) void embed_ln_kernel(
    const u16* __restrict__ Ahi, const u16* __restrict__ Alo,
    const u16* __restrict__ Whi, const u16* __restrict__ Wlo,
    const float* __restrict__ bias,
    const float* __restrict__ g, const float* __restrict__ bb,
    float* __restrict__ feat, u16* hnh, u16* hnl)
{
    constexpr int BM = 64, BN = 256, K = 256, SA = 40;
    __shared__ u16 AsH[BM * SA], AsL[BM * SA];
    __shared__ u16 WsH[BN * SA], WsL[BN * SA];
    __shared__ float wred[BM][4];
    int tid = threadIdx.x;
    int m0 = blockIdx.x * BM;
    int lane = tid & 63, wn = tid >> 6;
    int fr = lane & 15, quad = lane >> 4;
    f32x4 acc[4][4] = {};

    for (int k0 = 0; k0 < K; k0 += 32) {
        {
            int s = tid;             // BM*4 == 256
            int row = s >> 2, seg = s & 3;
            long off = (long)(m0 + row) * 256 + k0 + seg * 8;
            *(uint4*)&AsH[row * SA + seg * 8] = *(const uint4*)(Ahi + off);
            *(uint4*)&AsL[row * SA + seg * 8] = *(const uint4*)(Alo + off);
        }
#pragma unroll
        for (int it = 0; it < 4; it++) {
            int s = tid + it * 256;
            int row = s >> 2, seg = s & 3;
            long off = (long)row * 256 + k0 + seg * 8;
            *(uint4*)&WsH[row * SA + seg * 8] = *(const uint4*)(Whi + off);
            *(uint4*)&WsL[row * SA + seg * 8] = *(const uint4*)(Wlo + off);
        }
        __syncthreads();
        bf16x8 aH[4], aL[4], bH[4], bL[4];
#pragma unroll
        for (int im = 0; im < 4; im++) {
            int r = im * 16 + fr;
            aH[im] = *(const bf16x8*)&AsH[r * SA + quad * 8];
            aL[im] = *(const bf16x8*)&AsL[r * SA + quad * 8];
        }
#pragma unroll
        for (int in = 0; in < 4; in++) {
            int r = wn * 64 + in * 16 + fr;
            bH[in] = *(const bf16x8*)&WsH[r * SA + quad * 8];
            bL[in] = *(const bf16x8*)&WsL[r * SA + quad * 8];
        }
#pragma unroll
        for (int im = 0; im < 4; im++)
#pragma unroll
            for (int in = 0; in < 4; in++)
                acc[im][in] = mfma3(aH[im], aL[im], bH[in], bL[in], acc[im][in]);
        __syncthreads();
    }

    // ---- fused epilogue: +bias, feat store, LN, bf16 hn store ----
    int   col[4];
    float gv[4], bbv[4];
    float v[4][4][4];   // [im][in][reg]
#pragma unroll
    for (int in = 0; in < 4; in++) {
        col[in] = wn * 64 + in * 16 + fr;
        float bs = bias[col[in]];
        gv[in] = g[col[in]];
        bbv[in] = bb[col[in]];
#pragma unroll
        for (int im = 0; im < 4; im++)
#pragma unroll
            for (int reg = 0; reg < 4; reg++)
                v[im][in][reg] = acc[im][in][reg] + bs;
    }
#pragma unroll
    for (int im = 0; im < 4; im++)
#pragma unroll
        for (int reg = 0; reg < 4; reg++) {
            long gr = m0 + im * 16 + quad * 4 + reg;
#pragma unroll
            for (int in = 0; in < 4; in++)
                feat[gr * 256 + col[in]] = v[im][in][reg];
        }
    // pass 1: row means
    float s1[4][4];
#pragma unroll
    for (int im = 0; im < 4; im++)
#pragma unroll
        for (int reg = 0; reg < 4; reg++) {
            float s = v[im][0][reg] + v[im][1][reg] + v[im][2][reg] + v[im][3][reg];
            s += __shfl_xor(s, 1, 64); s += __shfl_xor(s, 2, 64);
            s += __shfl_xor(s, 4, 64); s += __shfl_xor(s, 8, 64);
            s1[im][reg] = s;
        }
    if (fr == 0)
#pragma unroll
        for (int im = 0; im < 4; im++)
#pragma unroll
            for (int reg = 0; reg < 4; reg++)
                wred[im * 16 + quad * 4 + reg][wn] = s1[im][reg];
    __syncthreads();
    float mu[4][4];
#pragma unroll
    for (int im = 0; im < 4; im++)
#pragma unroll
        for (int reg = 0; reg < 4; reg++) {
            int row = im * 16 + quad * 4 + reg;
            mu[im][reg] = (wred[row][0] + wred[row][1] + wred[row][2] + wred[row][3]) * (1.f / 256.f);
        }
    __syncthreads();
    // pass 2: row variance
#pragma unroll
    for (int im = 0; im < 4; im++)
#pragma unroll
        for (int reg = 0; reg < 4; reg++) {
            float m = mu[im][reg];
            float d0 = v[im][0][reg] - m, d1 = v[im][1][reg] - m;
            float d2 = v[im][2][reg] - m, d3 = v[im][3][reg] - m;
            float s = d0 * d0 + d1 * d1 + d2 * d2 + d3 * d3;
            s += __shfl_xor(s, 1, 64); s += __shfl_xor(s, 2, 64);
            s += __shfl_xor(s, 4, 64); s += __shfl_xor(s, 8, 64);
            s1[im][reg] = s;
        }
    if (fr == 0)
#pragma unroll
        for (int im = 0; im < 4; im++)
#pragma unroll
            for (int reg = 0; reg < 4; reg++)
                wred[im * 16 + quad * 4 + reg][wn] = s1[im][reg];
    __syncthreads();
#pragma unroll
    for (int im = 0; im < 4; im++)
#pragma unroll
        for (int reg = 0; reg < 4; reg++) {
            int row = im * 16 + quad * 4 + reg;
            float var = (wred[row][0] + wred[row][1] + wred[row][2] + wred[row][3]) * (1.f / 256.f);
            float rstd = rsqrtf(var + 1e-5f);
            long gr = m0 + row;
#pragma unroll
            for (int in = 0; in < 4; in++) {
                float o = (v[im][in][reg] - mu[im][reg]) * rstd * gv[in] + bbv[in];
                u16 h, l;
                split2(o, h, l);
                hnh[gr * 256 + col[in]] = h;
                hnl[gr * 256 + col[in]] = l;
            }
        }
}

// ---------------------------------------------------------------------------
// out_proj GEMM + residual + post-LN + pool partials fused.
// BM=64, BN=256, K=512. A = y bf16 hi/lo [M,512]; W = opw hi/lo [256,512].
// Writes blockpart[blk][256] = sum over 64 rows of LN output (no HBM LN buf).
// ---------------------------------------------------------------------------
__global__ __launch_bounds__(256) void outproj_ln_pool_kernel(
    const u16* __restrict__ Ahi, const u16* __restrict__ Alo,
    const u16* __restrict__ Whi, const u16* __restrict__ Wlo,
    const float* __restrict__ resid,
    const float* __restrict__ g, const float* __restrict__ bb,
    float* __restrict__ blockpart)
{
    constexpr int BM = 64, BN = 256, K = 512, SA = 40;
    __shared__ u16 AsH[BM * SA], AsL[BM * SA];
    __shared__ u16 WsH[BN * SA], WsL[BN * SA];
    __shared__ float wred[BM][4];
    int tid = threadIdx.x;
    int m0 = blockIdx.x * BM;
    int lane = tid & 63, wn = tid >> 6;
    int fr = lane & 15, quad = lane >> 4;
    f32x4 acc[4][4] = {};

    for (int k0 = 0; k0 < K; k0 += 32) {
        {
            int s = tid;
            int row = s >> 2, seg = s & 3;
            long off = (long)(m0 + row) * 512 + k0 + seg * 8;
            *(uint4*)&AsH[row * SA + seg * 8] = *(const uint4*)(Ahi + off);
            *(uint4*)&AsL[row * SA + seg * 8] = *(const uint4*)(Alo + off);
        }
#pragma unroll
        for (int it = 0; it < 4; it++) {
            int s = tid + it * 256;
            int row = s >> 2, seg = s & 3;
            long off = (long)row * 512 + k0 + seg * 8;
            *(uint4*)&WsH[row * SA + seg * 8] = *(const uint4*)(Whi + off);
            *(uint4*)&WsL[row * SA + seg * 8] = *(const uint4*)(Wlo + off);
        }
        __syncthreads();
        bf16x8 aH[4], aL[4], bH[4], bL[4];
#pragma unroll
        for (int im = 0; im < 4; im++) {
            int r = im * 16 + fr;
            aH[im] = *(const bf16x8*)&AsH[r * SA + quad * 8];
            aL[im] = *(const bf16x8*)&AsL[r * SA + quad * 8];
        }
#pragma unroll
        for (int in = 0; in < 4; in++) {
            int r = wn * 64 + in * 16 + fr;
            bH[in] = *(const bf16x8*)&WsH[r * SA + quad * 8];
            bL[in] = *(const bf16x8*)&WsL[r * SA + quad * 8];
        }
#pragma unroll
        for (int im = 0; im < 4; im++)
#pragma unroll
            for (int in = 0; in < 4; in++)
                acc[im][in] = mfma3(aH[im], aL[im], bH[in], bL[in], acc[im][in]);
        __syncthreads();
    }

    // ---- epilogue: +resid, LN, pool partial ----
    int   col[4];
    float gv[4], bbv[4];
    float v[4][4][4];
#pragma unroll
    for (int in = 0; in < 4; in++) {
        col[in] = wn * 64 + in * 16 + fr;
        gv[in] = g[col[in]];
        bbv[in] = bb[col[in]];
    }
#pragma unroll
    for (int im = 0; im < 4; im++)
#pragma unroll
        for (int reg = 0; reg < 4; reg++) {
            long gr = m0 + im * 16 + quad * 4 + reg;
#pragma unroll
            for (int in = 0; in < 4; in++)
                v[im][in][reg] = acc[im][in][reg] + resid[gr * 256 + col[in]];
        }
    // row mean
    float s1[4][4];
#pragma unroll
    for (int im = 0; im < 4; im++)
#pragma unroll
        for (int reg = 0; reg < 4; reg++) {
            float s = v[im][0][reg] + v[im][1][reg] + v[im][2][reg] + v[im][3][reg];
            s += __shfl_xor(s, 1, 64); s += __shfl_xor(s, 2, 64);
            s += __shfl_xor(s, 4, 64); s += __shfl_xor(s, 8, 64);
            s1[im][reg] = s;
        }
    if (fr == 0)
#pragma unroll
        for (int im = 0; im < 4; im++)
#pragma unroll
            for (int reg = 0; reg < 4; reg++)
                wred[im * 16 + quad * 4 + reg][wn] = s1[im][reg];
    __syncthreads();
    float mu[4][4];
#pragma unroll
    for (int im = 0; im < 4; im++)
#pragma unroll
        for (int reg = 0; reg < 4; reg++) {
            int row = im * 16 + quad * 4 + reg;
            mu[im][reg] = (wred[row][0] + wred[row][1] + wred[row][2] + wred[row][3]) * (1.f / 256.f);
        }
    __syncthreads();
    // row variance
#pragma unroll
    for (int im = 0; im < 4; im++)
#pragma unroll
        for (int reg = 0; reg < 4; reg++) {
            float m = mu[im][reg];
            float d0 = v[im][0][reg] - m, d1 = v[im][1][reg] - m;
            float d2 = v[im][2][reg] - m, d3 = v[im][3][reg] - m;
            float s = d0 * d0 + d1 * d1 + d2 * d2 + d3 * d3;
            s += __shfl_xor(s, 1, 64); s += __shfl_xor(s, 2, 64);
            s += __shfl_xor(s, 4, 64); s += __shfl_xor(s, 8, 64);
            s1[im][reg] = s;
        }
    if (fr == 0)
#pragma unroll
        for (int im = 0; im < 4; im++)
#pragma unroll
            for (int reg = 0; reg < 4; reg++)
                wred[im * 16 + quad * 4 + reg][wn] = s1[im][reg];
    __syncthreads();
    // LN output (in v) and column partial sums over the block's 64 rows
    float p[4] = {0.f, 0.f, 0.f, 0.f};
#pragma unroll
    for (int im = 0; im < 4; im++)
#pragma unroll
        for (int reg = 0; reg < 4; reg++) {
            int row = im * 16 + quad * 4 + reg;
            float var = (wred[row][0] + wred[row][1] + wred[row][2] + wred[row][3]) * (1.f / 256.f);
            float rstd = rsqrtf(var + 1e-5f);
#pragma unroll
            for (int in = 0; in < 4; in++) {
                float o = (v[im][in][reg] - mu[im][reg]) * rstd * gv[in] + bbv[in];
                p[in] += o;
            }
        }
#pragma unroll
    for (int in = 0; in < 4; in++) {
        p[in] += __shfl_xor(p[in], 16, 64);
        p[in] += __shfl_xor(p[in], 32, 64);
    }
    if (quad == 0)
#pragma unroll
        for (int in = 0; in < 4; in++)
            blockpart[(long)blockIdx.x * 256 + col[in]] = p[in];
}

// ---------------------------------------------------------------------------
// Causal depthwise conv (k=4) + SiLU -> xm bf16 hi/lo
// ---------------------------------------------------------------------------
__global__ __launch_bounds__(256) void conv_silu_kernel(const float* __restrict__ xz,
                                                        const float* __restrict__ cw,
                                                        const float* __restrict__ cb,
                                                        u16* __restrict__ xmh,
                                                        u16* __restrict__ xml) {
    int r = blockIdx.x;
    int d = blockIdx.y * 256 + threadIdx.x;
    int t = r & (Tt - 1);
    float w0 = cw[d * 4 + 0], w1 = cw[d * 4 + 1], w2 = cw[d * 4 + 2], w3 = cw[d * 4 + 3];
    float acc = cb[d];
    acc += w3 * xz[(long)r * 1024 + d];
    if (t >= 1) acc += w2 * xz[(long)(r - 1) * 1024 + d];
    if (t >= 2) acc += w1 * xz[(long)(r - 2) * 1024 + d];
    if (t >= 3) acc += w0 * xz[(long)(r - 3) * 1024 + d];
    float s = acc / (1.f + __expf(-acc));
    u16 h, l;
    split2(s, h, l);
    xmh[(long)r * 512 + d] = h;
    xml[(long)r * 512 + d] = l;
}

// ---------------------------------------------------------------------------
// Chunked selective scan with fused dt_proj (NC=64, CL=16), native exp.
// ---------------------------------------------------------------------------
__device__ inline float delta_inline(const float* __restrict__ dblrow,
                                     const float4 wd[4], float bias) {
    float4 t0 = *(const float4*)(dblrow + 0);
    float4 t1 = *(const float4*)(dblrow + 4);
    float4 t2 = *(const float4*)(dblrow + 8);
    float4 t3 = *(const float4*)(dblrow + 12);
    float s = bias;
    s += t0.x * wd[0].x + t0.y * wd[0].y + t0.z * wd[0].z + t0.w * wd[0].w;
    s += t1.x * wd[1].x + t1.y * wd[1].y + t1.z * wd[1].z + t1.w * wd[1].w;
    s += t2.x * wd[2].x + t2.y * wd[2].y + t2.z * wd[2].z + t2.w * wd[2].w;
    s += t3.x * wd[3].x + t3.y * wd[3].y + t3.z * wd[3].z + t3.w * wd[3].w;
    return softplus_fast(s);
}

__global__ __launch_bounds__(64) void scan_p1(const float* __restrict__ dbl,
                                              const float* __restrict__ dtw,
                                              const float* __restrict__ dtb,
                                              const u16* __restrict__ xmh,
                                              const u16* __restrict__ xml,
                                              const float* __restrict__ A_log,
                                              float* __restrict__ chunkS,
                                              float* __restrict__ sumdelta) {
    int b = blockIdx.x;
    int c = blockIdx.y;
    int d = blockIdx.z * 64 + threadIdx.x;
    float Arow[16];
#pragma unroll
    for (int n = 0; n < 16; n++) Arow[n] = -expf(A_log[d * 16 + n]);
    float4 wd[4];
#pragma unroll
    for (int q = 0; q < 4; q++) wd[q] = *(const float4*)(dtw + d * 16 + q * 4);
    float bdt = dtb[d];
    float S[16];
#pragma unroll
    for (int n = 0; n < 16; n++) S[n] = 0.f;
    float sd = 0.f;
    long r0 = (long)b * Tt + (long)c * CL;

    for (int t = 0; t < CL; t++) {
        long r = r0 + t;
        float dl = delta_inline(dbl + r * 48, wd, bdt);
        float u  = bf2f(xmh[r * 512 + d]) + bf2f(xml[r * 512 + d]);
        float du = dl * u;
        sd += dl;
        float Bn[16];
        const float4* Bp = (const float4*)(dbl + r * 48 + 16);
#pragma unroll
        for (int q = 0; q < 4; q++) {
            float4 bv = Bp[q];
            Bn[q*4+0] = bv.x; Bn[q*4+1] = bv.y; Bn[q*4+2] = bv.z; Bn[q*4+3] = bv.w;
        }
#pragma unroll
        for (int n = 0; n < 16; n++) {
            float a = __expf(dl * Arow[n]);
            S[n] = a * S[n] + du * Bn[n];
        }
    }
    long base = ((long)(b * NC + c) * 16) * 512 + d;
#pragma unroll
    for (int n = 0; n < 16; n++) chunkS[base + (long)n * 512] = S[n];
    sumdelta[(long)(b * NC + c) * 512 + d] = sd;
}

__global__ __launch_bounds__(256) void scan_combine(float* chunkS,
                                                    const float* __restrict__ sumdelta,
                                                    const float* __restrict__ A_log) {
    int idx = blockIdx.x * 256 + threadIdx.x;
    int d = idx & 511;
    int n = (idx >> 9) & 15;
    int b = idx >> 13;
    float Aval = -expf(A_log[d * 16 + n]);
    float h = 0.f;
    for (int c = 0; c < NC; c++) {
        long si = ((long)(b * NC + c) * 16 + n) * 512 + d;
        float s = chunkS[si];
        float a = __expf(Aval * sumdelta[(long)(b * NC + c) * 512 + d]);
        chunkS[si] = h;
        h = a * h + s;
    }
}

__global__ __launch_bounds__(64) void scan_p2(const float* __restrict__ dbl,
                                              const float* __restrict__ dtw,
                                              const float* __restrict__ dtb,
                                              const u16* xmh, const u16* xml,
                                              const float* __restrict__ xz,
                                              const float* __restrict__ A_log,
                                              const float* __restrict__ Dv,
                                              const float* __restrict__ chunkH,
                                              u16* yh, u16* yl) {
    int b = blockIdx.x;
    int c = blockIdx.y;
    int d = blockIdx.z * 64 + threadIdx.x;
    float Arow[16];
#pragma unroll
    for (int n = 0; n < 16; n++) Arow[n] = -expf(A_log[d * 16 + n]);
    float4 wd[4];
#pragma unroll
    for (int q = 0; q < 4; q++) wd[q] = *(const float4*)(dtw + d * 16 + q * 4);
    float bdt = dtb[d];
    float Dd = Dv[d];
    float h[16];
    long base = ((long)(b * NC + c) * 16) * 512 + d;
#pragma unroll
    for (int n = 0; n < 16; n++) h[n] = chunkH[base + (long)n * 512];
    long r0 = (long)b * Tt + (long)c * CL;

    for (int t = 0; t < CL; t++) {
        long r = r0 + t;
        float dl  = delta_inline(dbl + r * 48, wd, bdt);
        float u   = bf2f(xmh[r * 512 + d]) + bf2f(xml[r * 512 + d]);
        float res = xz[r * 1024 + 512 + d];
        float du  = dl * u;
        float Bn[16], Cn[16];
        const float4* Bp = (const float4*)(dbl + r * 48 + 16);
        const float4* Cp = (const float4*)(dbl + r * 48 + 32);
#pragma unroll
        for (int q = 0; q < 4; q++) {
            float4 bv = Bp[q];
            float4 cv = Cp[q];
            Bn[q*4+0] = bv.x; Bn[q*4+1] = bv.y; Bn[q*4+2] = bv.z; Bn[q*4+3] = bv.w;
            Cn[q*4+0] = cv.x; Cn[q*4+1] = cv.y; Cn[q*4+2] = cv.z; Cn[q*4+3] = cv.w;
        }
        float ysum = 0.f;
#pragma unroll
        for (int n = 0; n < 16; n++) {
            float a = __expf(dl * Arow[n]);
            h[n] = a * h[n] + du * Bn[n];
            ysum += h[n] * Cn[n];
        }
        float yy = ysum + u * Dd;
        float sres = res / (1.f + __expf(-res));
        float outv = yy * sres;
        u16 hh, ll;
        split2(outv, hh, ll);
        yh[r * 512 + d] = hh;
        yl[r * 512 + d] = ll;
    }
}

// ---------------------------------------------------------------------------
// head: reduce 16 block partials per batch -> pooled, then classify
// ---------------------------------------------------------------------------
__global__ __launch_bounds__(256) void head_kernel(const float* __restrict__ bp,
                                                   const float* __restrict__ fw,
                                                   const float* __restrict__ fb,
                                                   float* __restrict__ out) {
    __shared__ float pld[256];
    int b = blockIdx.x;
    int d = threadIdx.x;
    float s = 0.f;
#pragma unroll
    for (int i = 0; i < 16; i++)
        s += bp[(long)(b * 16 + i) * 256 + d];
    pld[d] = s;
    __syncthreads();
    if (d < N_CLASSES) {
        float acc = 0.f;
        for (int k = 0; k < 256; k++) acc += pld[k] * fw[d * 256 + k];
        out[b * N_CLASSES + d] = acc * (1.f / (float)Tt) + fb[d];
    }
}

// ---------------------------------------------------------------------------
extern "C" void kernel_launch(void* const* d_in, const int* in_sizes, int n_in,
                              void* d_out, int out_size, void* d_ws, size_t ws_size,
                              hipStream_t stream) {
    const float* x         = (const float*)d_in[0];
    const float* embed_w   = (const float*)d_in[1];
    const float* embed_b   = (const float*)d_in[2];
    const float* pre_g     = (const float*)d_in[3];
    const float* pre_b     = (const float*)d_in[4];
    const float* in_proj_w = (const float*)d_in[5];
    const float* conv_w    = (const float*)d_in[6];
    const float* conv_b    = (const float*)d_in[7];
    const float* x_proj_w  = (const float*)d_in[8];
    const float* dt_proj_w = (const float*)d_in[9];
    const float* dt_proj_b = (const float*)d_in[10];
    const float* A_log     = (const float*)d_in[11];
    const float* Dv        = (const float*)d_in[12];
    const float* out_proj_w= (const float*)d_in[13];
    const float* post_g    = (const float*)d_in[14];
    const float* post_b    = (const float*)d_in[15];
    const float* fine_w    = (const float*)d_in[16];
    const float* fine_b    = (const float*)d_in[17];
    float* out = (float*)d_out;
    char* base = (char*)d_ws;

    // workspace layout (bytes) — total ~88.6 MB
    float* feat     = (float*)(base + 0);          //  8 MB fp32 [M,256]
    float* xz       = (float*)(base + 8388608);    // 32 MB fp32 [M,1024]
    float* chunkS   = (float*)(base + 41943040);   // 16 MB [8*NC,16,512]
    u16*   xmh      = (u16*)  (base + 58720256);   //  8 MB bf16 [M,512] (-> y hi)
    u16*   xml      = (u16*)  (base + 67108864);   //  8 MB bf16 [M,512] (-> y lo)
    u16*   fbh      = (u16*)  (base + 75497472);   //  4 MB featbf hi -> hn hi
    u16*   fbl      = (u16*)  (base + 79691776);   //  4 MB featbf lo -> hn lo
    float* dbl      = (float*)(base + 83886080);   //  1.5 MB fp32 [M,48]
    float* sumdelta = (float*)(base + 85458944);   //  1 MB
    float* blockpart= (float*)(base + 86507520);   //  128 KB [128][256]
    u16*   ebh      = (u16*)  (base + 86638592);   // weight bf16 buffers (~1.9 MB)
    u16*   ebl      = ebh + 65536;
    u16*   iph      = ebl + 65536;
    u16*   ipl      = iph + 262144;
    u16*   xph      = ipl + 262144;
    u16*   xpl      = xph + 24576;
    u16*   oph      = xpl + 24576;
    u16*   opl      = oph + 131072;

    // 1. featurize + weight conversion (one dispatch)
    prep_kernel<<<dim3(Mrows + 1888), dim3(256), 0, stream>>>(
        x, fbh, fbl, embed_w, in_proj_w, x_proj_w, out_proj_w,
        ebh, ebl, iph, ipl, xph, xpl, oph, opl);

    // 2. embed GEMM + bias + pre-LN -> feat fp32, hn bf16 (in-place over featbf)
    embed_ln_kernel<<<dim3(Mrows / 64), dim3(256), 0, stream>>>(
        fbh, fbl, ebh, ebl, embed_b, pre_g, pre_b, feat, fbh, fbl);

    // 3. in_proj: xz = hn @ ipw^T  (M=8192,N=1024,K=256)
    gemm_mfma<128,128><<<dim3(8, 64), dim3(256), 0, stream>>>(
        fbh, fbl, 256, iph, ipl, 256, xz, 1024, Mrows, 1024, 256);

    // 4. conv + silu -> xm bf16 hi/lo
    conv_silu_kernel<<<dim3(Mrows, 2), dim3(256), 0, stream>>>(xz, conv_w, conv_b, xmh, xml);

    // 5. x_proj: dbl = xm @ xpw^T  (M=8192,N=48,K=512)
    gemm_mfma<64,64><<<dim3(1, 128), dim3(256), 0, stream>>>(
        xmh, xml, 512, xph, xpl, 512, dbl, 48, Mrows, 48, 512);

    // 6. chunked selective scan (dt_proj fused); p2 writes y bf16 over xm
    scan_p1<<<dim3(Bb, NC, 8), dim3(64), 0, stream>>>(
        dbl, dt_proj_w, dt_proj_b, xmh, xml, A_log, chunkS, sumdelta);
    scan_combine<<<dim3(256), dim3(256), 0, stream>>>(chunkS, sumdelta, A_log);
    scan_p2<<<dim3(Bb, NC, 8), dim3(64), 0, stream>>>(
        dbl, dt_proj_w, dt_proj_b, xmh, xml, xz, A_log, Dv, chunkS, xmh, xml);

    // 7. out_proj + residual + post-LN + pool partials (one dispatch)
    outproj_ln_pool_kernel<<<dim3(Mrows / 64), dim3(256), 0, stream>>>(
        xmh, xml, oph, opl, feat, post_g, post_b, blockpart);

    // 8. head (pool reduce + classify)
    head_kernel<<<dim3(Bb), dim3(256), 0, stream>>>(blockpart, fine_w, fine_b, out);
}

// Round 7
// 259.117 us; speedup vs baseline: 5.5282x; 1.0502x over previous
//
#include <hip/hip_runtime.h>
#include <hip/hip_bf16.h>
#include <math.h>

// Problem constants
#define Bb 8
#define Tt 1024
#define Jj 25
#define D_MODEL 256
#define D_STATE 16
#define D_CONV 4
#define D_INNER 512
#define DT_RANK 16
#define N_CLASSES 60
#define Mrows (Bb*Tt)   // 8192
#define NC 64           // scan chunks
#define CL 16           // chunk length (NC*CL == Tt)

typedef unsigned short u16;
using bf16x8 = __attribute__((ext_vector_type(8))) __bf16;
using f32x4  = __attribute__((ext_vector_type(4))) float;

// ---- bf16 split helpers ----------------------------------------------------
__device__ inline u16 f2bf(float x) {
    unsigned u = __float_as_uint(x);
    unsigned r = (u + 0x7fffu + ((u >> 16) & 1u)) >> 16;
    return (u16)r;
}
__device__ inline float bf2f(u16 h) { return __uint_as_float((unsigned)h << 16); }
__device__ inline void split2(float x, u16& h, u16& l) {
    h = f2bf(x);
    l = f2bf(x - bf2f(h));
}
__device__ inline float softplus_fast(float s) {
    return fmaxf(s, 0.f) + __logf(1.f + __expf(-fabsf(s)));
}
__device__ inline f32x4 mfma3(bf16x8 ah, bf16x8 al, bf16x8 bh, bf16x8 bl, f32x4 c) {
    c = __builtin_amdgcn_mfma_f32_16x16x32_bf16(al, bh, c, 0, 0, 0);
    c = __builtin_amdgcn_mfma_f32_16x16x32_bf16(ah, bl, c, 0, 0, 0);
    c = __builtin_amdgcn_mfma_f32_16x16x32_bf16(ah, bh, c, 0, 0, 0);
    return c;
}

// ---------------------------------------------------------------------------
// prep: blocks 0..8191 featurize -> fh/fl; blocks 8192.. weight cvt
// ---------------------------------------------------------------------------
__global__ __launch_bounds__(256) void prep_kernel(
    const float* __restrict__ x, u16* __restrict__ fh, u16* __restrict__ fl,
    const float* __restrict__ ew, const float* __restrict__ iw,
    const float* __restrict__ xw, const float* __restrict__ ow,
    u16* __restrict__ ebh, u16* __restrict__ ebl,
    u16* __restrict__ iph, u16* __restrict__ ipl,
    u16* __restrict__ xph, u16* __restrict__ xpl,
    u16* __restrict__ oph, u16* __restrict__ opl) {
    int blk = blockIdx.x;
    if (blk < Mrows) {
        int r = blk;
        int c = threadIdx.x;
        float v = 0.f;
        if (c < 225) {
            int t = r & (Tt - 1);
            int j = c / 9;
            int cc = c - j * 9;
            int comp = cc % 3;
            int kind = cc / 3;
            auto POS = [&](int dt) -> float {
                const float* p = x + (long)(r - dt) * Jj * 3;
                return p[j * 3 + comp] - p[comp];
            };
            if (kind == 0) v = POS(0);
            else if (kind == 1) v = (t >= 1) ? (POS(0) - POS(1)) : 0.f;
            else {
                if (t >= 2)      v = POS(0) - 2.f * POS(1) + POS(2);
                else if (t == 1) v = POS(0) - POS(1);
                else             v = 0.f;
            }
        }
        u16 h, l;
        split2(v, h, l);
        fh[(long)r * 256 + c] = h;
        fl[(long)r * 256 + c] = l;
    } else {
        int i = (blk - Mrows) * 256 + threadIdx.x;   // 0..483327
        const float* src; u16 *dh, *dl; int K, kshift, idx;
        if (i < 65536)       { src = ew; dh = ebh; dl = ebl; K = 225; kshift = 8; idx = i; }
        else if (i < 327680) { src = iw; dh = iph; dl = ipl; K = 256; kshift = 8; idx = i - 65536; }
        else if (i < 352256) { src = xw; dh = xph; dl = xpl; K = 512; kshift = 9; idx = i - 327680; }
        else                 { src = ow; dh = oph; dl = opl; K = 512; kshift = 9; idx = i - 352256; }
        int n = idx >> kshift;
        int k = idx & ((1 << kshift) - 1);
        float v = (k < K) ? src[(long)n * K + k] : 0.f;
        u16 h, l;
        split2(v, h, l);
        dh[idx] = h;
        dl[idx] = l;
    }
}

// ---------------------------------------------------------------------------
// generic bf16x3 MFMA GEMM (in_proj)
// ---------------------------------------------------------------------------
template<int BM, int BN>
__global__ __launch_bounds__(256) void gemm_mfma(
    const u16* __restrict__ Ahi, const u16* __restrict__ Alo, int lda,
    const u16* __restrict__ Whi, const u16* __restrict__ Wlo, int ldw,
    float* __restrict__ C, int ldc, int M, int N, int K)
{
    constexpr int TM = BM / 32;
    constexpr int TN = BN / 32;
    constexpr int SA = 40;
    __shared__ u16 AsH[BM * SA], AsL[BM * SA];
    __shared__ u16 WsH[BN * SA], WsL[BN * SA];
    int tid = threadIdx.x;
    int m0 = blockIdx.y * BM;
    int n0 = blockIdx.x * BN;
    int lane = tid & 63;
    int wave = tid >> 6;
    int wm = wave >> 1, wn = wave & 1;
    int fr = lane & 15, quad = lane >> 4;
    f32x4 acc[TM][TN] = {};

    for (int k0 = 0; k0 < K; k0 += 32) {
        for (int s = tid; s < BM * 4; s += 256) {
            int row = s >> 2, seg = s & 3;
            long off = (long)(m0 + row) * lda + k0 + seg * 8;
            *(uint4*)&AsH[row * SA + seg * 8] = *(const uint4*)(Ahi + off);
            *(uint4*)&AsL[row * SA + seg * 8] = *(const uint4*)(Alo + off);
        }
        for (int s = tid; s < BN * 4; s += 256) {
            int row = s >> 2, seg = s & 3;
            long off = (long)(n0 + row) * ldw + k0 + seg * 8;
            *(uint4*)&WsH[row * SA + seg * 8] = *(const uint4*)(Whi + off);
            *(uint4*)&WsL[row * SA + seg * 8] = *(const uint4*)(Wlo + off);
        }
        __syncthreads();
        bf16x8 aH[TM], aL[TM], bH[TN], bL[TN];
#pragma unroll
        for (int im = 0; im < TM; im++) {
            int r = wm * (BM / 2) + im * 16 + fr;
            aH[im] = *(const bf16x8*)&AsH[r * SA + quad * 8];
            aL[im] = *(const bf16x8*)&AsL[r * SA + quad * 8];
        }
#pragma unroll
        for (int in = 0; in < TN; in++) {
            int r = wn * (BN / 2) + in * 16 + fr;
            bH[in] = *(const bf16x8*)&WsH[r * SA + quad * 8];
            bL[in] = *(const bf16x8*)&WsL[r * SA + quad * 8];
        }
#pragma unroll
        for (int im = 0; im < TM; im++)
#pragma unroll
            for (int in = 0; in < TN; in++)
                acc[im][in] = mfma3(aH[im], aL[im], bH[in], bL[in], acc[im][in]);
        __syncthreads();
    }
#pragma unroll
    for (int im = 0; im < TM; im++) {
#pragma unroll
        for (int in = 0; in < TN; in++) {
#pragma unroll
            for (int reg = 0; reg < 4; reg++) {
                int gm = m0 + wm * (BM / 2) + im * 16 + quad * 4 + reg;
                int gn = n0 + wn * (BN / 2) + in * 16 + fr;
                C[(long)gm * ldc + gn] = acc[im][in][reg];
            }
        }
    }
}

// ---------------------------------------------------------------------------
// embed GEMM + bias + pre-LN fused. BM=64, BN=256 (full row), K=256.
// ---------------------------------------------------------------------------
__global__ __launch_bounds__(256) void embed_ln_kernel(
    const u16* __restrict__ Ahi, const u16* __restrict__ Alo,
    const u16* __restrict__ Whi, const u16* __restrict__ Wlo,
    const float* __restrict__ bias,
    const float* __restrict__ g, const float* __restrict__ bb,
    float* __restrict__ feat, u16* hnh, u16* hnl)
{
    constexpr int BM = 64, K = 256, SA = 40;
    __shared__ u16 AsH[BM * SA], AsL[BM * SA];
    __shared__ u16 WsH[256 * SA], WsL[256 * SA];
    __shared__ float wred[BM][4];
    int tid = threadIdx.x;
    int m0 = blockIdx.x * BM;
    int lane = tid & 63, wn = tid >> 6;
    int fr = lane & 15, quad = lane >> 4;
    f32x4 acc[4][4] = {};

    for (int k0 = 0; k0 < K; k0 += 32) {
        {
            int s = tid;
            int row = s >> 2, seg = s & 3;
            long off = (long)(m0 + row) * 256 + k0 + seg * 8;
            *(uint4*)&AsH[row * SA + seg * 8] = *(const uint4*)(Ahi + off);
            *(uint4*)&AsL[row * SA + seg * 8] = *(const uint4*)(Alo + off);
        }
#pragma unroll
        for (int it = 0; it < 4; it++) {
            int s = tid + it * 256;
            int row = s >> 2, seg = s & 3;
            long off = (long)row * 256 + k0 + seg * 8;
            *(uint4*)&WsH[row * SA + seg * 8] = *(const uint4*)(Whi + off);
            *(uint4*)&WsL[row * SA + seg * 8] = *(const uint4*)(Wlo + off);
        }
        __syncthreads();
        bf16x8 aH[4], aL[4], bH[4], bL[4];
#pragma unroll
        for (int im = 0; im < 4; im++) {
            int r = im * 16 + fr;
            aH[im] = *(const bf16x8*)&AsH[r * SA + quad * 8];
            aL[im] = *(const bf16x8*)&AsL[r * SA + quad * 8];
        }
#pragma unroll
        for (int in = 0; in < 4; in++) {
            int r = wn * 64 + in * 16 + fr;
            bH[in] = *(const bf16x8*)&WsH[r * SA + quad * 8];
            bL[in] = *(const bf16x8*)&WsL[r * SA + quad * 8];
        }
#pragma unroll
        for (int im = 0; im < 4; im++)
#pragma unroll
            for (int in = 0; in < 4; in++)
                acc[im][in] = mfma3(aH[im], aL[im], bH[in], bL[in], acc[im][in]);
        __syncthreads();
    }

    int   col[4];
    float gv[4], bbv[4];
    float v[4][4][4];
#pragma unroll
    for (int in = 0; in < 4; in++) {
        col[in] = wn * 64 + in * 16 + fr;
        float bs = bias[col[in]];
        gv[in] = g[col[in]];
        bbv[in] = bb[col[in]];
#pragma unroll
        for (int im = 0; im < 4; im++)
#pragma unroll
            for (int reg = 0; reg < 4; reg++)
                v[im][in][reg] = acc[im][in][reg] + bs;
    }
#pragma unroll
    for (int im = 0; im < 4; im++)
#pragma unroll
        for (int reg = 0; reg < 4; reg++) {
            long gr = m0 + im * 16 + quad * 4 + reg;
#pragma unroll
            for (int in = 0; in < 4; in++)
                feat[gr * 256 + col[in]] = v[im][in][reg];
        }
    float s1[4][4];
#pragma unroll
    for (int im = 0; im < 4; im++)
#pragma unroll
        for (int reg = 0; reg < 4; reg++) {
            float s = v[im][0][reg] + v[im][1][reg] + v[im][2][reg] + v[im][3][reg];
            s += __shfl_xor(s, 1, 64); s += __shfl_xor(s, 2, 64);
            s += __shfl_xor(s, 4, 64); s += __shfl_xor(s, 8, 64);
            s1[im][reg] = s;
        }
    if (fr == 0)
#pragma unroll
        for (int im = 0; im < 4; im++)
#pragma unroll
            for (int reg = 0; reg < 4; reg++)
                wred[im * 16 + quad * 4 + reg][wn] = s1[im][reg];
    __syncthreads();
    float mu[4][4];
#pragma unroll
    for (int im = 0; im < 4; im++)
#pragma unroll
        for (int reg = 0; reg < 4; reg++) {
            int row = im * 16 + quad * 4 + reg;
            mu[im][reg] = (wred[row][0] + wred[row][1] + wred[row][2] + wred[row][3]) * (1.f / 256.f);
        }
    __syncthreads();
#pragma unroll
    for (int im = 0; im < 4; im++)
#pragma unroll
        for (int reg = 0; reg < 4; reg++) {
            float m = mu[im][reg];
            float d0 = v[im][0][reg] - m, d1 = v[im][1][reg] - m;
            float d2 = v[im][2][reg] - m, d3 = v[im][3][reg] - m;
            float s = d0 * d0 + d1 * d1 + d2 * d2 + d3 * d3;
            s += __shfl_xor(s, 1, 64); s += __shfl_xor(s, 2, 64);
            s += __shfl_xor(s, 4, 64); s += __shfl_xor(s, 8, 64);
            s1[im][reg] = s;
        }
    if (fr == 0)
#pragma unroll
        for (int im = 0; im < 4; im++)
#pragma unroll
            for (int reg = 0; reg < 4; reg++)
                wred[im * 16 + quad * 4 + reg][wn] = s1[im][reg];
    __syncthreads();
#pragma unroll
    for (int im = 0; im < 4; im++)
#pragma unroll
        for (int reg = 0; reg < 4; reg++) {
            int row = im * 16 + quad * 4 + reg;
            float var = (wred[row][0] + wred[row][1] + wred[row][2] + wred[row][3]) * (1.f / 256.f);
            float rstd = rsqrtf(var + 1e-5f);
            long gr = m0 + row;
#pragma unroll
            for (int in = 0; in < 4; in++) {
                float o = (v[im][in][reg] - mu[im][reg]) * rstd * gv[in] + bbv[in];
                u16 h, l;
                split2(o, h, l);
                hnh[gr * 256 + col[in]] = h;
                hnl[gr * 256 + col[in]] = l;
            }
        }
}

// ---------------------------------------------------------------------------
// Fused conv+SiLU+x_proj. BM=32 rows/block, grid 256. For each K-slice of 32:
// compute conv(xz)->silu->bf16 split in registers, store to LDS A-frags and
// global xm, then MFMA against the 48(->64 padded)-row x_proj W tile.
// ---------------------------------------------------------------------------
__global__ __launch_bounds__(256) void conv_xproj_kernel(
    const float* __restrict__ xz,
    const float* __restrict__ cw, const float* __restrict__ cb,
    const u16* __restrict__ Whi, const u16* __restrict__ Wlo,  // [48][512]
    u16* __restrict__ xmh, u16* __restrict__ xml,
    float* __restrict__ dbl)
{
    constexpr int SA = 40;
    __shared__ u16 AsH[32 * SA], AsL[32 * SA];
    __shared__ u16 WsH[64 * SA], WsL[64 * SA];
    int tid = threadIdx.x;
    int m0 = blockIdx.x * 32;
    int lane = tid & 63, wave = tid >> 6;
    int fr = lane & 15, quad = lane >> 4;
    int rtile = (wave & 1) * 16;
    int ctile = (wave >> 1) * 32;
    f32x4 acc[2] = {};

    int row = tid >> 3;          // 0..31
    int cg  = tid & 7;           // 4 cols each
    long gr = m0 + row;
    int t = gr & (Tt - 1);
    const float* xzr = xz + gr * 1024;

    for (int k0 = 0; k0 < 512; k0 += 32) {
        int c0 = k0 + cg * 4;
        // conv + silu for 4 cols
        float4 x0 = *(const float4*)(xzr + c0);
        float4 x1 = (t >= 1) ? *(const float4*)(xzr - 1024 + c0) : make_float4(0,0,0,0);
        float4 x2 = (t >= 2) ? *(const float4*)(xzr - 2048 + c0) : make_float4(0,0,0,0);
        float4 x3 = (t >= 3) ? *(const float4*)(xzr - 3072 + c0) : make_float4(0,0,0,0);
        float xs0[4] = {x0.x, x0.y, x0.z, x0.w};
        float xs1[4] = {x1.x, x1.y, x1.z, x1.w};
        float xs2[4] = {x2.x, x2.y, x2.z, x2.w};
        float xs3[4] = {x3.x, x3.y, x3.z, x3.w};
        u16 hh[4], ll[4];
#pragma unroll
        for (int j = 0; j < 4; j++) {
            float4 w = *(const float4*)(cw + (c0 + j) * 4);
            float a = cb[c0 + j] + w.w * xs0[j] + w.z * xs1[j] + w.y * xs2[j] + w.x * xs3[j];
            float s = a / (1.f + __expf(-a));
            split2(s, hh[j], ll[j]);
        }
        uint2 ph = *(uint2*)hh;
        uint2 pl = *(uint2*)ll;
        *(uint2*)(xmh + gr * 512 + c0) = ph;
        *(uint2*)(xml + gr * 512 + c0) = pl;
        *(uint2*)&AsH[row * SA + cg * 4] = ph;
        *(uint2*)&AsL[row * SA + cg * 4] = pl;
        // stage W tile (rows 0..47, pad 48..63 with zeros)
        {
            int wr = tid >> 2, seg = tid & 3;
            uint4 vh = make_uint4(0,0,0,0), vl = make_uint4(0,0,0,0);
            if (wr < 48) {
                long off = (long)wr * 512 + k0 + seg * 8;
                vh = *(const uint4*)(Whi + off);
                vl = *(const uint4*)(Wlo + off);
            }
            *(uint4*)&WsH[wr * SA + seg * 8] = vh;
            *(uint4*)&WsL[wr * SA + seg * 8] = vl;
        }
        __syncthreads();
        bf16x8 aH, aL, bH[2], bL[2];
        aH = *(const bf16x8*)&AsH[(rtile + fr) * SA + quad * 8];
        aL = *(const bf16x8*)&AsL[(rtile + fr) * SA + quad * 8];
#pragma unroll
        for (int in = 0; in < 2; in++) {
            int r = ctile + in * 16 + fr;
            bH[in] = *(const bf16x8*)&WsH[r * SA + quad * 8];
            bL[in] = *(const bf16x8*)&WsL[r * SA + quad * 8];
        }
#pragma unroll
        for (int in = 0; in < 2; in++)
            acc[in] = mfma3(aH, aL, bH[in], bL[in], acc[in]);
        __syncthreads();
    }
#pragma unroll
    for (int in = 0; in < 2; in++) {
#pragma unroll
        for (int reg = 0; reg < 4; reg++) {
            int gm = m0 + rtile + quad * 4 + reg;
            int gn = ctile + in * 16 + fr;
            if (gn < 48)
                dbl[(long)gm * 48 + gn] = acc[in][reg];
        }
    }
}

// ---------------------------------------------------------------------------
// out_proj GEMM + residual + post-LN + pool partials fused.
// ---------------------------------------------------------------------------
__global__ __launch_bounds__(256) void outproj_ln_pool_kernel(
    const u16* __restrict__ Ahi, const u16* __restrict__ Alo,
    const u16* __restrict__ Whi, const u16* __restrict__ Wlo,
    const float* __restrict__ resid,
    const float* __restrict__ g, const float* __restrict__ bb,
    float* __restrict__ blockpart)
{
    constexpr int BM = 64, K = 512, SA = 40;
    __shared__ u16 AsH[BM * SA], AsL[BM * SA];
    __shared__ u16 WsH[256 * SA], WsL[256 * SA];
    __shared__ float wred[BM][4];
    int tid = threadIdx.x;
    int m0 = blockIdx.x * BM;
    int lane = tid & 63, wn = tid >> 6;
    int fr = lane & 15, quad = lane >> 4;
    f32x4 acc[4][4] = {};

    for (int k0 = 0; k0 < K; k0 += 32) {
        {
            int s = tid;
            int row = s >> 2, seg = s & 3;
            long off = (long)(m0 + row) * 512 + k0 + seg * 8;
            *(uint4*)&AsH[row * SA + seg * 8] = *(const uint4*)(Ahi + off);
            *(uint4*)&AsL[row * SA + seg * 8] = *(const uint4*)(Alo + off);
        }
#pragma unroll
        for (int it = 0; it < 4; it++) {
            int s = tid + it * 256;
            int row = s >> 2, seg = s & 3;
            long off = (long)row * 512 + k0 + seg * 8;
            *(uint4*)&WsH[row * SA + seg * 8] = *(const uint4*)(Whi + off);
            *(uint4*)&WsL[row * SA + seg * 8] = *(const uint4*)(Wlo + off);
        }
        __syncthreads();
        bf16x8 aH[4], aL[4], bH[4], bL[4];
#pragma unroll
        for (int im = 0; im < 4; im++) {
            int r = im * 16 + fr;
            aH[im] = *(const bf16x8*)&AsH[r * SA + quad * 8];
            aL[im] = *(const bf16x8*)&AsL[r * SA + quad * 8];
        }
#pragma unroll
        for (int in = 0; in < 4; in++) {
            int r = wn * 64 + in * 16 + fr;
            bH[in] = *(const bf16x8*)&WsH[r * SA + quad * 8];
            bL[in] = *(const bf16x8*)&WsL[r * SA + quad * 8];
        }
#pragma unroll
        for (int im = 0; im < 4; im++)
#pragma unroll
            for (int in = 0; in < 4; in++)
                acc[im][in] = mfma3(aH[im], aL[im], bH[in], bL[in], acc[im][in]);
        __syncthreads();
    }

    int   col[4];
    float gv[4], bbv[4];
    float v[4][4][4];
#pragma unroll
    for (int in = 0; in < 4; in++) {
        col[in] = wn * 64 + in * 16 + fr;
        gv[in] = g[col[in]];
        bbv[in] = bb[col[in]];
    }
#pragma unroll
    for (int im = 0; im < 4; im++)
#pragma unroll
        for (int reg = 0; reg < 4; reg++) {
            long gr = m0 + im * 16 + quad * 4 + reg;
#pragma unroll
            for (int in = 0; in < 4; in++)
                v[im][in][reg] = acc[im][in][reg] + resid[gr * 256 + col[in]];
        }
    float s1[4][4];
#pragma unroll
    for (int im = 0; im < 4; im++)
#pragma unroll
        for (int reg = 0; reg < 4; reg++) {
            float s = v[im][0][reg] + v[im][1][reg] + v[im][2][reg] + v[im][3][reg];
            s += __shfl_xor(s, 1, 64); s += __shfl_xor(s, 2, 64);
            s += __shfl_xor(s, 4, 64); s += __shfl_xor(s, 8, 64);
            s1[im][reg] = s;
        }
    if (fr == 0)
#pragma unroll
        for (int im = 0; im < 4; im++)
#pragma unroll
            for (int reg = 0; reg < 4; reg++)
                wred[im * 16 + quad * 4 + reg][wn] = s1[im][reg];
    __syncthreads();
    float mu[4][4];
#pragma unroll
    for (int im = 0; im < 4; im++)
#pragma unroll
        for (int reg = 0; reg < 4; reg++) {
            int row = im * 16 + quad * 4 + reg;
            mu[im][reg] = (wred[row][0] + wred[row][1] + wred[row][2] + wred[row][3]) * (1.f / 256.f);
        }
    __syncthreads();
#pragma unroll
    for (int im = 0; im < 4; im++)
#pragma unroll
        for (int reg = 0; reg < 4; reg++) {
            float m = mu[im][reg];
            float d0 = v[im][0][reg] - m, d1 = v[im][1][reg] - m;
            float d2 = v[im][2][reg] - m, d3 = v[im][3][reg] - m;
            float s = d0 * d0 + d1 * d1 + d2 * d2 + d3 * d3;
            s += __shfl_xor(s, 1, 64); s += __shfl_xor(s, 2, 64);
            s += __shfl_xor(s, 4, 64); s += __shfl_xor(s, 8, 64);
            s1[im][reg] = s;
        }
    if (fr == 0)
#pragma unroll
        for (int im = 0; im < 4; im++)
#pragma unroll
            for (int reg = 0; reg < 4; reg++)
                wred[im * 16 + quad * 4 + reg][wn] = s1[im][reg];
    __syncthreads();
    float p[4] = {0.f, 0.f, 0.f, 0.f};
#pragma unroll
    for (int im = 0; im < 4; im++)
#pragma unroll
        for (int reg = 0; reg < 4; reg++) {
            int row = im * 16 + quad * 4 + reg;
            float var = (wred[row][0] + wred[row][1] + wred[row][2] + wred[row][3]) * (1.f / 256.f);
            float rstd = rsqrtf(var + 1e-5f);
#pragma unroll
            for (int in = 0; in < 4; in++) {
                float o = (v[im][in][reg] - mu[im][reg]) * rstd * gv[in] + bbv[in];
                p[in] += o;
            }
        }
#pragma unroll
    for (int in = 0; in < 4; in++) {
        p[in] += __shfl_xor(p[in], 16, 64);
        p[in] += __shfl_xor(p[in], 32, 64);
    }
    if (quad == 0)
#pragma unroll
        for (int in = 0; in < 4; in++)
            blockpart[(long)blockIdx.x * 256 + col[in]] = p[in];
}

// ---------------------------------------------------------------------------
// Chunked selective scan, 512-thread blocks, LDS-staged dbl slab, fused dt_proj.
// Grid (Bb, NC). Thread d = 0..511.
// ---------------------------------------------------------------------------
__global__ __launch_bounds__(512) void scan_p1(const float* __restrict__ dbl,
                                               const float* __restrict__ dtw,
                                               const float* __restrict__ dtb,
                                               const u16* __restrict__ xmh,
                                               const u16* __restrict__ xml,
                                               const float* __restrict__ A_log,
                                               float* __restrict__ chunkS,
                                               float* __restrict__ sumdelta) {
    __shared__ float ds[CL * 48];
    int b = blockIdx.x, c = blockIdx.y, d = threadIdx.x;
    long r0 = (long)b * Tt + (long)c * CL;
    for (int i = d; i < CL * 48; i += 512) ds[i] = dbl[r0 * 48 + i];

    float Arow[16];
#pragma unroll
    for (int n = 0; n < 16; n++) Arow[n] = -expf(A_log[d * 16 + n]);
    float4 wd[4];
#pragma unroll
    for (int q = 0; q < 4; q++) wd[q] = *(const float4*)(dtw + d * 16 + q * 4);
    float bdt = dtb[d];
    float S[16];
#pragma unroll
    for (int n = 0; n < 16; n++) S[n] = 0.f;
    float sd = 0.f;
    __syncthreads();

    for (int t = 0; t < CL; t++) {
        const float* row = ds + t * 48;
        float4 t0 = *(const float4*)(row + 0);
        float4 t1 = *(const float4*)(row + 4);
        float4 t2 = *(const float4*)(row + 8);
        float4 t3 = *(const float4*)(row + 12);
        float s = bdt;
        s += t0.x * wd[0].x + t0.y * wd[0].y + t0.z * wd[0].z + t0.w * wd[0].w;
        s += t1.x * wd[1].x + t1.y * wd[1].y + t1.z * wd[1].z + t1.w * wd[1].w;
        s += t2.x * wd[2].x + t2.y * wd[2].y + t2.z * wd[2].z + t2.w * wd[2].w;
        s += t3.x * wd[3].x + t3.y * wd[3].y + t3.z * wd[3].z + t3.w * wd[3].w;
        float dl = softplus_fast(s);
        long r = r0 + t;
        float u = bf2f(xmh[r * 512 + d]) + bf2f(xml[r * 512 + d]);
        float du = dl * u;
        sd += dl;
        float Bn[16];
#pragma unroll
        for (int q = 0; q < 4; q++) {
            float4 bv = *(const float4*)(row + 16 + q * 4);
            Bn[q*4+0] = bv.x; Bn[q*4+1] = bv.y; Bn[q*4+2] = bv.z; Bn[q*4+3] = bv.w;
        }
#pragma unroll
        for (int n = 0; n < 16; n++) {
            float a = __expf(dl * Arow[n]);
            S[n] = a * S[n] + du * Bn[n];
        }
    }
    long base = ((long)(b * NC + c) * 16) * 512 + d;
#pragma unroll
    for (int n = 0; n < 16; n++) chunkS[base + (long)n * 512] = S[n];
    sumdelta[(long)(b * NC + c) * 512 + d] = sd;
}

__global__ __launch_bounds__(256) void scan_combine(float* chunkS,
                                                    const float* __restrict__ sumdelta,
                                                    const float* __restrict__ A_log) {
    int idx = blockIdx.x * 256 + threadIdx.x;
    int d = idx & 511;
    int n = (idx >> 9) & 15;
    int b = idx >> 13;
    float Aval = -expf(A_log[d * 16 + n]);
    float h = 0.f;
    for (int c = 0; c < NC; c++) {
        long si = ((long)(b * NC + c) * 16 + n) * 512 + d;
        float s = chunkS[si];
        float a = __expf(Aval * sumdelta[(long)(b * NC + c) * 512 + d]);
        chunkS[si] = h;
        h = a * h + s;
    }
}

__global__ __launch_bounds__(512) void scan_p2(const float* __restrict__ dbl,
                                               const float* __restrict__ dtw,
                                               const float* __restrict__ dtb,
                                               const u16* xmh, const u16* xml,
                                               const float* __restrict__ xz,
                                               const float* __restrict__ A_log,
                                               const float* __restrict__ Dv,
                                               const float* __restrict__ chunkH,
                                               u16* yh, u16* yl) {
    __shared__ float ds[CL * 48];
    int b = blockIdx.x, c = blockIdx.y, d = threadIdx.x;
    long r0 = (long)b * Tt + (long)c * CL;
    for (int i = d; i < CL * 48; i += 512) ds[i] = dbl[r0 * 48 + i];

    float Arow[16];
#pragma unroll
    for (int n = 0; n < 16; n++) Arow[n] = -expf(A_log[d * 16 + n]);
    float4 wd[4];
#pragma unroll
    for (int q = 0; q < 4; q++) wd[q] = *(const float4*)(dtw + d * 16 + q * 4);
    float bdt = dtb[d];
    float Dd = Dv[d];
    float h[16];
    long base = ((long)(b * NC + c) * 16) * 512 + d;
#pragma unroll
    for (int n = 0; n < 16; n++) h[n] = chunkH[base + (long)n * 512];
    __syncthreads();

    for (int t = 0; t < CL; t++) {
        const float* row = ds + t * 48;
        float4 t0 = *(const float4*)(row + 0);
        float4 t1 = *(const float4*)(row + 4);
        float4 t2 = *(const float4*)(row + 8);
        float4 t3 = *(const float4*)(row + 12);
        float s = bdt;
        s += t0.x * wd[0].x + t0.y * wd[0].y + t0.z * wd[0].z + t0.w * wd[0].w;
        s += t1.x * wd[1].x + t1.y * wd[1].y + t1.z * wd[1].z + t1.w * wd[1].w;
        s += t2.x * wd[2].x + t2.y * wd[2].y + t2.z * wd[2].z + t2.w * wd[2].w;
        s += t3.x * wd[3].x + t3.y * wd[3].y + t3.z * wd[3].z + t3.w * wd[3].w;
        float dl = softplus_fast(s);
        long r = r0 + t;
        float u = bf2f(xmh[r * 512 + d]) + bf2f(xml[r * 512 + d]);
        float res = xz[r * 1024 + 512 + d];
        float du = dl * u;
        float Bn[16], Cn[16];
#pragma unroll
        for (int q = 0; q < 4; q++) {
            float4 bv = *(const float4*)(row + 16 + q * 4);
            float4 cv = *(const float4*)(row + 32 + q * 4);
            Bn[q*4+0] = bv.x; Bn[q*4+1] = bv.y; Bn[q*4+2] = bv.z; Bn[q*4+3] = bv.w;
            Cn[q*4+0] = cv.x; Cn[q*4+1] = cv.y; Cn[q*4+2] = cv.z; Cn[q*4+3] = cv.w;
        }
        float ysum = 0.f;
#pragma unroll
        for (int n = 0; n < 16; n++) {
            float a = __expf(dl * Arow[n]);
            h[n] = a * h[n] + du * Bn[n];
            ysum += h[n] * Cn[n];
        }
        float yy = ysum + u * Dd;
        float sres = res / (1.f + __expf(-res));
        float outv = yy * sres;
        u16 hh, ll;
        split2(outv, hh, ll);
        yh[r * 512 + d] = hh;
        yl[r * 512 + d] = ll;
    }
}

// ---------------------------------------------------------------------------
// head: reduce 128 block partials -> pooled, classify
// ---------------------------------------------------------------------------
__global__ __launch_bounds__(256) void head_kernel(const float* __restrict__ bp,
                                                   const float* __restrict__ fw,
                                                   const float* __restrict__ fb,
                                                   float* __restrict__ out) {
    __shared__ float pld[256];
    int b = blockIdx.x;
    int d = threadIdx.x;
    float s = 0.f;
#pragma unroll
    for (int i = 0; i < 16; i++)
        s += bp[(long)(b * 16 + i) * 256 + d];
    pld[d] = s;
    __syncthreads();
    if (d < N_CLASSES) {
        float acc = 0.f;
        for (int k = 0; k < 256; k++) acc += pld[k] * fw[d * 256 + k];
        out[b * N_CLASSES + d] = acc * (1.f / (float)Tt) + fb[d];
    }
}

// ---------------------------------------------------------------------------
extern "C" void kernel_launch(void* const* d_in, const int* in_sizes, int n_in,
                              void* d_out, int out_size, void* d_ws, size_t ws_size,
                              hipStream_t stream) {
    const float* x         = (const float*)d_in[0];
    const float* embed_w   = (const float*)d_in[1];
    const float* embed_b   = (const float*)d_in[2];
    const float* pre_g     = (const float*)d_in[3];
    const float* pre_b     = (const float*)d_in[4];
    const float* in_proj_w = (const float*)d_in[5];
    const float* conv_w    = (const float*)d_in[6];
    const float* conv_b    = (const float*)d_in[7];
    const float* x_proj_w  = (const float*)d_in[8];
    const float* dt_proj_w = (const float*)d_in[9];
    const float* dt_proj_b = (const float*)d_in[10];
    const float* A_log     = (const float*)d_in[11];
    const float* Dv        = (const float*)d_in[12];
    const float* out_proj_w= (const float*)d_in[13];
    const float* post_g    = (const float*)d_in[14];
    const float* post_b    = (const float*)d_in[15];
    const float* fine_w    = (const float*)d_in[16];
    const float* fine_b    = (const float*)d_in[17];
    float* out = (float*)d_out;
    char* base = (char*)d_ws;

    // workspace layout (bytes) — total ~88.6 MB
    float* feat     = (float*)(base + 0);          //  8 MB fp32 [M,256]
    float* xz       = (float*)(base + 8388608);    // 32 MB fp32 [M,1024]
    float* chunkS   = (float*)(base + 41943040);   // 16 MB [8*NC,16,512]
    u16*   xmh      = (u16*)  (base + 58720256);   //  8 MB bf16 [M,512] (-> y hi)
    u16*   xml      = (u16*)  (base + 67108864);   //  8 MB bf16 [M,512] (-> y lo)
    u16*   fbh      = (u16*)  (base + 75497472);   //  4 MB featbf hi -> hn hi
    u16*   fbl      = (u16*)  (base + 79691776);   //  4 MB featbf lo -> hn lo
    float* dbl      = (float*)(base + 83886080);   //  1.5 MB fp32 [M,48]
    float* sumdelta = (float*)(base + 85458944);   //  1 MB
    float* blockpart= (float*)(base + 86507520);   //  128 KB [128][256]
    u16*   ebh      = (u16*)  (base + 86638592);   // weight bf16 buffers (~1.9 MB)
    u16*   ebl      = ebh + 65536;
    u16*   iph      = ebl + 65536;
    u16*   ipl      = iph + 262144;
    u16*   xph      = ipl + 262144;
    u16*   xpl      = xph + 24576;
    u16*   oph      = xpl + 24576;
    u16*   opl      = oph + 131072;

    // 1. featurize + weight conversion
    prep_kernel<<<dim3(Mrows + 1888), dim3(256), 0, stream>>>(
        x, fbh, fbl, embed_w, in_proj_w, x_proj_w, out_proj_w,
        ebh, ebl, iph, ipl, xph, xpl, oph, opl);

    // 2. embed GEMM + bias + pre-LN -> feat fp32, hn bf16 (in-place over featbf)
    embed_ln_kernel<<<dim3(Mrows / 64), dim3(256), 0, stream>>>(
        fbh, fbl, ebh, ebl, embed_b, pre_g, pre_b, feat, fbh, fbl);

    // 3. in_proj: xz = hn @ ipw^T  (M=8192,N=1024,K=256)
    gemm_mfma<128,128><<<dim3(8, 64), dim3(256), 0, stream>>>(
        fbh, fbl, 256, iph, ipl, 256, xz, 1024, Mrows, 1024, 256);

    // 4. fused conv+silu+x_proj -> xm bf16 + dbl
    conv_xproj_kernel<<<dim3(Mrows / 32), dim3(256), 0, stream>>>(
        xz, conv_w, conv_b, xph, xpl, xmh, xml, dbl);

    // 5. chunked selective scan (dt_proj fused); p2 writes y bf16 over xm
    scan_p1<<<dim3(Bb, NC), dim3(512), 0, stream>>>(
        dbl, dt_proj_w, dt_proj_b, xmh, xml, A_log, chunkS, sumdelta);
    scan_combine<<<dim3(256), dim3(256), 0, stream>>>(chunkS, sumdelta, A_log);
    scan_p2<<<dim3(Bb, NC), dim3(512), 0, stream>>>(
        dbl, dt_proj_w, dt_proj_b, xmh, xml, xz, A_log, Dv, chunkS, xmh, xml);

    // 6. out_proj + residual + post-LN + pool partials
    outproj_ln_pool_kernel<<<dim3(Mrows / 64), dim3(256), 0, stream>>>(
        xmh, xml, oph, opl, feat, post_g, post_b, blockpart);

    // 7. head
    head_kernel<<<dim3(Bb), dim3(256), 0, stream>>>(blockpart, fine_w, fine_b, out);
}